// Round 8
// baseline (318.704 us; speedup 1.0000x reference)
//
#include <hip/hip_runtime.h>
#include <hip/hip_bf16.h>

using bf16 = __hip_bfloat16;
using bf16x8 = __attribute__((ext_vector_type(8))) short;
using f32x4  = __attribute__((ext_vector_type(4))) float;

__device__ inline unsigned short f2bu(float f){ bf16 h = __float2bfloat16(f); return *(unsigned short*)&h; }
__device__ inline void async_cp16(const void* g, void* l){
  __builtin_amdgcn_global_load_lds((const __attribute__((address_space(1))) void*)g,
                                   (__attribute__((address_space(3))) void*)l, 16, 0, 0);
}
union BF8 { unsigned short s[8]; bf16x8 v; };

constexpr int D_ = 1024, L_ = 2048;
constexpr int CN = 384;   // Cbig row stride (floats)

// ---------------------------------------------------------------------------
__global__ __launch_bounds__(256) void k_qinit(const float* __restrict__ bq, float* __restrict__ q){
  int e = blockIdx.x*256 + threadIdx.x;
  q[e] = bq[e];
}

// q[e] += sum_d cq[d]*wq[e,d] ; grid 256 = (ec 0..15, ds 0..15), wave-reduce + atomic
__global__ __launch_bounds__(256) void k_q2(const float* __restrict__ cq, const float* __restrict__ wq,
                                            float* __restrict__ q){
  const int ec = blockIdx.x >> 4, ds = blockIdx.x & 15;
  const int w = threadIdx.x >> 6, lane = threadIdx.x & 63;
  const int d = ds*64 + lane;
  const float c = cq[d];
  const int e0 = ec*64 + w*16;
  #pragma unroll
  for (int j=0;j<16;++j){
    float p = c*wq[(size_t)(e0+j)*D_ + d];
    #pragma unroll
    for (int m=32;m>=1;m>>=1) p += __shfl_xor(p, m, 64);
    if (lane==0) atomicAdd(&q[e0+j], p);
  }
}

// qwk[hh][d] = sum_e q[hh*64+e]*wk[hh*64+e,d] ; grid 256 = (hh, dq), LDS reduce
__global__ __launch_bounds__(256) void k_qwk2(const float* __restrict__ q, const float* __restrict__ wk,
                                              float* __restrict__ qwk){
  __shared__ float red[4][64];
  const int hh = blockIdx.x >> 4, dq = blockIdx.x & 15;
  const int eg = threadIdx.x >> 6, dl = threadIdx.x & 63;
  const int d = dq*64 + dl;
  float s = 0.f;
  #pragma unroll
  for (int j=0;j<16;++j){
    int e = hh*64 + eg*16 + j;
    s += q[e]*wk[(size_t)e*D_ + d];
  }
  red[eg][dl] = s;
  __syncthreads();
  if (eg==0)
    qwk[hh*D_ + d] = (red[0][dl]+red[1][dl]) + (red[2][dl]+red[3][dl]);
}

// fp32 -> bf16 bulk convert (4 elems/thread), optional scale
__global__ __launch_bounds__(256) void k_cvt(const float* __restrict__ in, unsigned short* __restrict__ outp,
                                             float scale){
  int i = blockIdx.x*256 + threadIdx.x;
  float4 v = *(const float4*)(in + (size_t)4*i);
  *(ushort4*)(outp + (size_t)4*i) = make_ushort4(f2bu(v.x*scale), f2bu(v.y*scale),
                                                 f2bu(v.z*scale), f2bu(v.w*scale));
}

// Build Btb [384][1024] bf16: rows v*16+k = proj_w[v][dd][k] (transposed);
// rows 256+v = proj_b[v]+ce[v]. grid (16 ddchunk, 16 v).
__global__ __launch_bounds__(256) void k_tpB(const float* __restrict__ proj_w, const float* __restrict__ proj_b,
                                             const float* __restrict__ ce, unsigned short* __restrict__ Btb){
  __shared__ float t[64][17];
  const int tid = threadIdx.x;
  const int v = blockIdx.y, dd0 = blockIdx.x*64;
  { const int r = tid >> 2, kq = tid & 3;
    float4 a = *(const float4*)(proj_w + ((size_t)(v*D_ + dd0 + r))*16 + kq*4);
    t[r][kq*4+0]=a.x; t[r][kq*4+1]=a.y; t[r][kq*4+2]=a.z; t[r][kq*4+3]=a.w; }
  __syncthreads();
  { const int k = tid >> 4, c0 = (tid & 15)*4;
    ushort4 o = make_ushort4(f2bu(t[c0+0][k]), f2bu(t[c0+1][k]), f2bu(t[c0+2][k]), f2bu(t[c0+3][k]));
    *(ushort4*)(Btb + (size_t)(v*16+k)*D_ + dd0 + c0) = o; }
  if (tid < 16){
    const int c0 = tid*4;
    float4 pb = *(const float4*)(proj_b + v*D_ + dd0 + c0);
    float4 cc = *(const float4*)(ce     + v*D_ + dd0 + c0);
    ushort4 o = make_ushort4(f2bu(pb.x+cc.x), f2bu(pb.y+cc.y), f2bu(pb.z+cc.z), f2bu(pb.w+cc.w));
    *(ushort4*)(Btb + (size_t)(256+v)*D_ + dd0 + c0) = o;
  }
}

// Wb2[d][c] = bf16(Cbig[d][c]) for c<256 (natural B-fragment order: c = vp*32+k32)
__global__ __launch_bounds__(256) void k_wprep2(const float* __restrict__ Cbig, unsigned short* __restrict__ Wb2){
  const int idx = blockIdx.x*256 + threadIdx.x;   // 65536 = 1024 d x 64 c-quads
  const int d = idx >> 6, c4 = (idx & 63)*4;
  float4 v = *(const float4*)(Cbig + (size_t)d*CN + c4);
  *(ushort4*)(Wb2 + (size_t)d*256 + c4) = make_ushort4(f2bu(v.x), f2bu(v.y), f2bu(v.z), f2bu(v.w));
}

// ---------------------------------------------------------------------------
// unified GEMM: C fp32 [M][ldc] = A[M][K] * Bt[N][K]^T (+bias)
// BM=64, BN=128, BK=32; 4 waves, wave tile 32x64.
template<bool AFP32, bool BIAS>
__global__ __launch_bounds__(256) void k_gemm(const void* __restrict__ Av,
                                              const unsigned short* __restrict__ Bt,
                                              const float* __restrict__ bias,
                                              float* __restrict__ C,
                                              int K, int ldc, int Mvalid){
  __shared__ unsigned short As[64*32];
  __shared__ unsigned short Bs[128*32];
  const int tid = threadIdx.x;
  const int wave = tid >> 6, lane = tid & 63;
  const int wm = wave & 1, wn = wave >> 1;
  const int m0 = blockIdx.y*64, n0 = blockIdx.x*128;
  const int lm = lane & 15, kg4 = lane >> 4;
  f32x4 acc[2][4];
  #pragma unroll
  for (int mf=0;mf<2;++mf)
    #pragma unroll
    for (int nf=0;nf<4;++nf)
      acc[mf][nf] = (f32x4){0.f,0.f,0.f,0.f};
  const unsigned short* Abf = (const unsigned short*)Av;
  const float* Afp = (const float*)Av;
  const int arow = tid >> 2;
  const int akq  = (tid & 3) ^ ((tid >> 3) & 3);
  for (int k0=0; k0<K; k0+=32){
    if (!AFP32){
      async_cp16(Abf + (size_t)(m0+arow)*K + k0 + akq*8, &As[tid*8]);
    } else {
      const float* gp = Afp + (size_t)(m0+arow)*K + k0 + akq*8;
      float4 a0 = *(const float4*)gp, a1 = *(const float4*)(gp+4);
      *(ushort4*)(&As[tid*8])   = make_ushort4(f2bu(a0.x),f2bu(a0.y),f2bu(a0.z),f2bu(a0.w));
      *(ushort4*)(&As[tid*8+4]) = make_ushort4(f2bu(a1.x),f2bu(a1.y),f2bu(a1.z),f2bu(a1.w));
    }
    #pragma unroll
    for (int i=0;i<2;++i){
      int idx = i*256 + tid;
      int col = idx >> 2, kqg = (idx & 3) ^ ((idx >> 3) & 3);
      async_cp16(Bt + (size_t)(n0+col)*K + k0 + kqg*8, &Bs[idx*8]);
    }
    __syncthreads();
    bf16x8 af[2], bfr[4];
    #pragma unroll
    for (int f=0;f<2;++f){
      int row = wm*32 + f*16 + lm;
      af[f] = *(const bf16x8*)(&As[row*32 + ((kg4 ^ (row>>1)) & 3)*8 + (kg4 & ~3)*8]);
    }
    #pragma unroll
    for (int f=0;f<4;++f){
      int colr = wn*64 + f*16 + lm;
      bfr[f] = *(const bf16x8*)(&Bs[colr*32 + ((kg4 ^ (colr>>1)) & 3)*8 + (kg4 & ~3)*8]);
    }
    #pragma unroll
    for (int mf=0;mf<2;++mf)
      #pragma unroll
      for (int nf=0;nf<4;++nf)
        acc[mf][nf] = __builtin_amdgcn_mfma_f32_16x16x32_bf16(af[mf], bfr[nf], acc[mf][nf], 0,0,0);
    __syncthreads();
  }
  #pragma unroll
  for (int nf=0;nf<4;++nf){
    int col = n0 + wn*64 + nf*16 + lm;
    float bval = BIAS ? bias[col] : 0.f;
    #pragma unroll
    for (int mf=0;mf<2;++mf){
      #pragma unroll
      for (int r=0;r<4;++r){
        int row = m0 + wm*32 + mf*16 + kg4*4 + r;
        if (row < Mvalid) C[(size_t)row*ldc + col] = acc[mf][nf][r] + bval;
      }
    }
  }
}

// ---------------------------------------------------------------------------
// fused per-batch: MFMA wvp-term + scalar c0-term (exact R6 semantics) + P2.
// grid 128 (site-groups of 16), 4 waves; wave covers hh = wave*4+it.
__global__ __launch_bounds__(256) void k_fused5(const float* __restrict__ x, int bb,
                                                const float* __restrict__ Cbig,
                                                const unsigned short* __restrict__ Wb2,
                                                const float* __restrict__ bv,
                                                const float* __restrict__ P2,
                                                unsigned short* __restrict__ ctx){
  __shared__ float patchP[16*260];   // [s][v*16+k]
  __shared__ float attnT[16*320];    // [hh][s*20+v]
  const int tid = threadIdx.x;
  const int sg = blockIdx.x;
  { // phase A: thread (s, v) loads its 16-elem patch
    const int s = tid >> 4, v = tid & 15;
    const int l = sg*16 + s;
    const int hi = l >> 6, wi = l & 63;
    const float* xp = x + ((size_t)((bb*16+v)*128 + hi*4)*256 + wi*4);
    float* dst = &patchP[s*260 + v*16];
    #pragma unroll
    for (int pi=0; pi<4; ++pi){
      float4 r = *(const float4*)(xp + pi*256);
      dst[pi*4+0]=r.x; dst[pi*4+1]=r.y; dst[pi*4+2]=r.z; dst[pi*4+3]=r.w;
    }
  }
  __syncthreads();
  { // phase B: thread (s, hh): scores + softmax -> attnT
    const int s = tid >> 4, hh = tid & 15;
    const float* qrow = Cbig + (size_t)(1024+hh)*CN;
    const float* prow = &patchP[s*260];
    float sc[16];
    #pragma unroll
    for (int v=0; v<16; ++v){
      float a = qrow[256+v];
      const float* qp = qrow + v*16;
      const float* pp = prow + v*16;
      #pragma unroll
      for (int k=0;k<16;++k) a += qp[k]*pp[k];
      sc[v] = a;
    }
    float mx = sc[0];
    #pragma unroll
    for (int v=1;v<16;++v) mx = fmaxf(mx, sc[v]);
    float sum = 0.f;
    #pragma unroll
    for (int v=0;v<16;++v){ sc[v] = __expf(sc[v]-mx); sum += sc[v]; }
    float inv = 1.f/sum;
    float* arow = &attnT[hh*320 + s*20];
    #pragma unroll
    for (int v=0;v<16;++v) arow[v] = sc[v]*inv;
  }
  __syncthreads();
  // phase C
  const int wave = tid >> 6, lane = tid & 63;
  const int m = lane & 15, quad = lane >> 4;
  const int l0 = sg*16;
  for (int it=0; it<4; ++it){
    const int hh = wave*4 + it;
    const float* at = &attnT[hh*320];
    f32x4 acc[4];
    #pragma unroll
    for (int dt=0;dt<4;++dt) acc[dt] = (f32x4){0.f,0.f,0.f,0.f};
    #pragma unroll
    for (int vp=0; vp<8; ++vp){
      const int v = vp*2 + (quad>>1);
      const int k8 = (quad&1)*8;
      const float aw = at[m*20 + v];
      const float* pp = &patchP[m*260 + v*16 + k8];
      BF8 af;
      #pragma unroll
      for (int j=0;j<8;++j) af.s[j] = f2bu(aw*pp[j]);
      #pragma unroll
      for (int dt=0; dt<4; ++dt){
        const int d = hh*64 + dt*16 + m;
        const bf16x8 bf = *(const bf16x8*)(Wb2 + (size_t)d*256 + vp*32 + quad*8);
        acc[dt] = __builtin_amdgcn_mfma_f32_16x16x32_bf16(af.v, bf, acc[dt], 0,0,0);
      }
    }
    // scalar c0-term (R6 semantics) + P2 + store
    #pragma unroll
    for (int dt=0; dt<4; ++dt){
      const int d = hh*64 + dt*16 + m;
      const float* c0p = Cbig + (size_t)d*CN + 256;
      float c0v[16];
      #pragma unroll
      for (int j=0;j<4;++j){
        float4 t = *(const float4*)(c0p + 4*j);
        c0v[4*j+0]=t.x; c0v[4*j+1]=t.y; c0v[4*j+2]=t.z; c0v[4*j+3]=t.w;
      }
      const float bvd = bv[d];
      #pragma unroll
      for (int r=0;r<4;++r){
        const int s = quad*4 + r;
        float dot = bvd;   // sum_v attn = 1
        const float* as_ = at + s*20;
        #pragma unroll
        for (int v=0;v<16;++v) dot += as_[v]*c0v[v];
        ctx[(size_t)(l0+s)*D_ + d] = f2bu(acc[dt][r] + dot + P2[(size_t)(l0+s)*D_ + d]);
      }
    }
  }
}

// ---------------------------------------------------------------------------
extern "C" void kernel_launch(void* const* d_in, const int* in_sizes, int n_in,
                              void* d_out, int out_size, void* d_ws, size_t ws_size,
                              hipStream_t stream){
  const float* x      = (const float*)d_in[0];
  const float* proj_w = (const float*)d_in[1];
  const float* proj_b = (const float*)d_in[2];
  const float* ce     = (const float*)d_in[3];
  const float* pe     = (const float*)d_in[4];
  const float* cq     = (const float*)d_in[5];
  const float* wq     = (const float*)d_in[6];
  const float* wk     = (const float*)d_in[7];
  const float* wv     = (const float*)d_in[8];
  const float* bq     = (const float*)d_in[9];
  // bk (d_in[10]) cancels in softmax
  const float* bv     = (const float*)d_in[11];
  const float* wo     = (const float*)d_in[12];
  const float* bo     = (const float*)d_in[13];
  float* out = (float*)d_out;

  // workspace — peak 8,470,912 B (< proven 9,589,760)
  char* base = (char*)d_ws;
  float*          q    = (float*)(base);                            // 4 KB
  float*          qwk  = (float*)(base + 4096);                     // 64 KB -> 69,632
  unsigned short* ctxb = (unsigned short*)(base + 69632);           // [2048][1024] bf16 (region A, 4 MB)
  unsigned short* Ab   = (unsigned short*)(base + 69632);           // [1152][1024] bf16 (overlaps ctxb; dead before fused5)
  unsigned short* Btb  = (unsigned short*)(base + 69632 + 2359296); // [384][1024] bf16 (overlaps ctxb)
  float*          Cbig = (float*)(base + 4263936);                  // [1040][384] f32 -> 5,861,376
  unsigned short* wo_b = (unsigned short*)(base + 5861376);         // [1024][1024] bf16 -> 7,958,528
  unsigned short* Wb2  = (unsigned short*)(base + 7958528);         // [1024][256] bf16 -> 8,470,912
  float*          P2   = out + (size_t)L_*D_;                       // pe·wv^T staged in d_out batch-1 half

  k_qinit<<<4,   256, 0, stream>>>(bq, q);
  k_q2   <<<256, 256, 0, stream>>>(cq, wq, q);
  k_qwk2 <<<256, 256, 0, stream>>>(q, wk, qwk);
  k_cvt  <<<1024,256, 0, stream>>>(wv, Ab, 1.0f);                       // Ab rows 0..1023 = bf16(wv)
  k_cvt  <<<16,  256, 0, stream>>>(qwk, Ab + (size_t)1024*D_, 0.125f);  // rows 1024..1039 = qwk/8
  k_cvt  <<<1024,256, 0, stream>>>(wo, wo_b, 1.0f);
  k_tpB  <<<dim3(16,16), 256, 0, stream>>>(proj_w, proj_b, ce, Btb);
  // Cbig = [wv; qwk/8] · [proj_w^T; pb+ce]^T
  k_gemm<false,false><<<dim3(3,17), 256, 0, stream>>>(Ab, Btb, nullptr, Cbig, 1024, CN, 1040);
  k_wprep2<<<256, 256, 0, stream>>>(Cbig, Wb2);
  // P2 = pe · wv^T  (R6-verified fp32-A path)
  k_gemm<true,false><<<dim3(8,32), 256, 0, stream>>>(pe, Ab, nullptr, P2, 1024, 1024, 2048);
  for (int b = 0; b < 2; ++b){
    k_fused5<<<128, 256, 0, stream>>>(x, b, Cbig, Wb2, bv, P2, ctxb);
    // out_b = ctx·wo^T + bo   (K=1024, all-bf16)
    k_gemm<false,true><<<dim3(8,32), 256, 0, stream>>>(ctxb, wo_b, bo, out + (size_t)b*L_*D_, 1024, 1024, 2048);
  }
}

// Round 9
// 245.010 us; speedup vs baseline: 1.3008x; 1.3008x over previous
//
#include <hip/hip_runtime.h>
#include <hip/hip_bf16.h>

using bf16 = __hip_bfloat16;
using bf16x8 = __attribute__((ext_vector_type(8))) short;
using f32x4  = __attribute__((ext_vector_type(4))) float;

__device__ inline unsigned short f2bu(float f){ bf16 h = __float2bfloat16(f); return *(unsigned short*)&h; }
__device__ inline void async_cp16(const void* g, void* l){
  __builtin_amdgcn_global_load_lds((const __attribute__((address_space(1))) void*)g,
                                   (__attribute__((address_space(3))) void*)l, 16, 0, 0);
}
union BF8 { unsigned short s[8]; bf16x8 v; };

constexpr int D_ = 1024, L_ = 2048;
constexpr int CN = 384;   // Cbig row stride (floats)

// ---------------------------------------------------------------------------
__global__ __launch_bounds__(256) void k_qinit(const float* __restrict__ bq, float* __restrict__ q){
  int e = blockIdx.x*256 + threadIdx.x;
  q[e] = bq[e];
}

// q[e] += sum_d cq[d]*wq[e,d] ; grid 256 = (ec 0..15, ds 0..15), wave-reduce + atomic
__global__ __launch_bounds__(256) void k_q2(const float* __restrict__ cq, const float* __restrict__ wq,
                                            float* __restrict__ q){
  const int ec = blockIdx.x >> 4, ds = blockIdx.x & 15;
  const int w = threadIdx.x >> 6, lane = threadIdx.x & 63;
  const int d = ds*64 + lane;
  const float c = cq[d];
  const int e0 = ec*64 + w*16;
  #pragma unroll
  for (int j=0;j<16;++j){
    float p = c*wq[(size_t)(e0+j)*D_ + d];
    #pragma unroll
    for (int m=32;m>=1;m>>=1) p += __shfl_xor(p, m, 64);
    if (lane==0) atomicAdd(&q[e0+j], p);
  }
}

// qwk[hh][d] = sum_e q[hh*64+e]*wk[hh*64+e,d] ; grid 256 = (hh, dq), LDS reduce
__global__ __launch_bounds__(256) void k_qwk2(const float* __restrict__ q, const float* __restrict__ wk,
                                              float* __restrict__ qwk){
  __shared__ float red[4][64];
  const int hh = blockIdx.x >> 4, dq = blockIdx.x & 15;
  const int eg = threadIdx.x >> 6, dl = threadIdx.x & 63;
  const int d = dq*64 + dl;
  float s = 0.f;
  #pragma unroll
  for (int j=0;j<16;++j){
    int e = hh*64 + eg*16 + j;
    s += q[e]*wk[(size_t)e*D_ + d];
  }
  red[eg][dl] = s;
  __syncthreads();
  if (eg==0)
    qwk[hh*D_ + d] = (red[0][dl]+red[1][dl]) + (red[2][dl]+red[3][dl]);
}

// fp32 -> bf16 bulk convert (4 elems/thread), optional scale
__global__ __launch_bounds__(256) void k_cvt(const float* __restrict__ in, unsigned short* __restrict__ outp,
                                             float scale){
  int i = blockIdx.x*256 + threadIdx.x;
  float4 v = *(const float4*)(in + (size_t)4*i);
  *(ushort4*)(outp + (size_t)4*i) = make_ushort4(f2bu(v.x*scale), f2bu(v.y*scale),
                                                 f2bu(v.z*scale), f2bu(v.w*scale));
}

// Build Btb [384][1024] bf16: rows v*16+k = proj_w[v][dd][k] (transposed);
// rows 256+v = proj_b[v]+ce[v]. grid (16 ddchunk, 16 v).
__global__ __launch_bounds__(256) void k_tpB(const float* __restrict__ proj_w, const float* __restrict__ proj_b,
                                             const float* __restrict__ ce, unsigned short* __restrict__ Btb){
  __shared__ float t[64][17];
  const int tid = threadIdx.x;
  const int v = blockIdx.y, dd0 = blockIdx.x*64;
  { const int r = tid >> 2, kq = tid & 3;
    float4 a = *(const float4*)(proj_w + ((size_t)(v*D_ + dd0 + r))*16 + kq*4);
    t[r][kq*4+0]=a.x; t[r][kq*4+1]=a.y; t[r][kq*4+2]=a.z; t[r][kq*4+3]=a.w; }
  __syncthreads();
  { const int k = tid >> 4, c0 = (tid & 15)*4;
    ushort4 o = make_ushort4(f2bu(t[c0+0][k]), f2bu(t[c0+1][k]), f2bu(t[c0+2][k]), f2bu(t[c0+3][k]));
    *(ushort4*)(Btb + (size_t)(v*16+k)*D_ + dd0 + c0) = o; }
  if (tid < 16){
    const int c0 = tid*4;
    float4 pb = *(const float4*)(proj_b + v*D_ + dd0 + c0);
    float4 cc = *(const float4*)(ce     + v*D_ + dd0 + c0);
    ushort4 o = make_ushort4(f2bu(pb.x+cc.x), f2bu(pb.y+cc.y), f2bu(pb.z+cc.z), f2bu(pb.w+cc.w));
    *(ushort4*)(Btb + (size_t)(256+v)*D_ + dd0 + c0) = o;
  }
}

// Wb2[d][c] = bf16(Cbig[d][c]) for c<256 (natural B-fragment order: c = vp*32+k32)
__global__ __launch_bounds__(256) void k_wprep2(const float* __restrict__ Cbig, unsigned short* __restrict__ Wb2){
  const int idx = blockIdx.x*256 + threadIdx.x;   // 65536 = 1024 d x 64 c-quads
  const int d = idx >> 6, c4 = (idx & 63)*4;
  float4 v = *(const float4*)(Cbig + (size_t)d*CN + c4);
  *(ushort4*)(Wb2 + (size_t)d*256 + c4) = make_ushort4(f2bu(v.x), f2bu(v.y), f2bu(v.z), f2bu(v.w));
}

// ---------------------------------------------------------------------------
// unified GEMM: C fp32 [M][ldc] = A[M][K] * Bt[N][K]^T (+bias)
// BM=64, BN=128, BK=32; 4 waves, wave tile 32x64.
template<bool AFP32, bool BIAS>
__global__ __launch_bounds__(256) void k_gemm(const void* __restrict__ Av,
                                              const unsigned short* __restrict__ Bt,
                                              const float* __restrict__ bias,
                                              float* __restrict__ C,
                                              int K, int ldc, int Mvalid){
  __shared__ unsigned short As[64*32];
  __shared__ unsigned short Bs[128*32];
  const int tid = threadIdx.x;
  const int wave = tid >> 6, lane = tid & 63;
  const int wm = wave & 1, wn = wave >> 1;
  const int m0 = blockIdx.y*64, n0 = blockIdx.x*128;
  const int lm = lane & 15, kg4 = lane >> 4;
  f32x4 acc[2][4];
  #pragma unroll
  for (int mf=0;mf<2;++mf)
    #pragma unroll
    for (int nf=0;nf<4;++nf)
      acc[mf][nf] = (f32x4){0.f,0.f,0.f,0.f};
  const unsigned short* Abf = (const unsigned short*)Av;
  const float* Afp = (const float*)Av;
  const int arow = tid >> 2;
  const int akq  = (tid & 3) ^ ((tid >> 3) & 3);
  for (int k0=0; k0<K; k0+=32){
    if (!AFP32){
      async_cp16(Abf + (size_t)(m0+arow)*K + k0 + akq*8, &As[tid*8]);
    } else {
      const float* gp = Afp + (size_t)(m0+arow)*K + k0 + akq*8;
      float4 a0 = *(const float4*)gp, a1 = *(const float4*)(gp+4);
      *(ushort4*)(&As[tid*8])   = make_ushort4(f2bu(a0.x),f2bu(a0.y),f2bu(a0.z),f2bu(a0.w));
      *(ushort4*)(&As[tid*8+4]) = make_ushort4(f2bu(a1.x),f2bu(a1.y),f2bu(a1.z),f2bu(a1.w));
    }
    #pragma unroll
    for (int i=0;i<2;++i){
      int idx = i*256 + tid;
      int col = idx >> 2, kqg = (idx & 3) ^ ((idx >> 3) & 3);
      async_cp16(Bt + (size_t)(n0+col)*K + k0 + kqg*8, &Bs[idx*8]);
    }
    __syncthreads();
    bf16x8 af[2], bfr[4];
    #pragma unroll
    for (int f=0;f<2;++f){
      int row = wm*32 + f*16 + lm;
      af[f] = *(const bf16x8*)(&As[row*32 + ((kg4 ^ (row>>1)) & 3)*8 + (kg4 & ~3)*8]);
    }
    #pragma unroll
    for (int f=0;f<4;++f){
      int colr = wn*64 + f*16 + lm;
      bfr[f] = *(const bf16x8*)(&Bs[colr*32 + ((kg4 ^ (colr>>1)) & 3)*8 + (kg4 & ~3)*8]);
    }
    #pragma unroll
    for (int mf=0;mf<2;++mf)
      #pragma unroll
      for (int nf=0;nf<4;++nf)
        acc[mf][nf] = __builtin_amdgcn_mfma_f32_16x16x32_bf16(af[mf], bfr[nf], acc[mf][nf], 0,0,0);
    __syncthreads();
  }
  #pragma unroll
  for (int nf=0;nf<4;++nf){
    int col = n0 + wn*64 + nf*16 + lm;
    float bval = BIAS ? bias[col] : 0.f;
    #pragma unroll
    for (int mf=0;mf<2;++mf){
      #pragma unroll
      for (int r=0;r<4;++r){
        int row = m0 + wm*32 + mf*16 + kg4*4 + r;
        if (row < Mvalid) C[(size_t)row*ldc + col] = acc[mf][nf][r] + bval;
      }
    }
  }
}

// ---------------------------------------------------------------------------
// fused, both batches in one launch: grid 512 = (bb 1b) x (sg 7b) x (hq 1b).
// Block: 16 sites x 8 heads; 4 waves, wave covers h8 = wave*2+it (it 0..1).
// Math identical to verified R8 fused5 (MFMA wvp-term + scalar c0-term + P2).
__global__ __launch_bounds__(256) void k_fused6(const float* __restrict__ x,
                                                const float* __restrict__ Cbig,
                                                const unsigned short* __restrict__ Wb2,
                                                const float* __restrict__ bv,
                                                const float* __restrict__ P2,
                                                unsigned short* __restrict__ ctx0,
                                                unsigned short* __restrict__ ctx1){
  __shared__ float patchP[16*260];   // [s][v*16+k]
  __shared__ float attnT[8*320];     // [h8][s*20+v]
  const int tid = threadIdx.x;
  const int bb = blockIdx.x >> 8;
  const int sg = (blockIdx.x >> 1) & 127;
  const int hq = blockIdx.x & 1;
  unsigned short* ctx = bb ? ctx1 : ctx0;
  { // phase A: thread (s, v) loads its 16-elem patch
    const int s = tid >> 4, v = tid & 15;
    const int l = sg*16 + s;
    const int hi = l >> 6, wi = l & 63;
    const float* xp = x + ((size_t)((bb*16+v)*128 + hi*4)*256 + wi*4);
    float* dst = &patchP[s*260 + v*16];
    #pragma unroll
    for (int pi=0; pi<4; ++pi){
      float4 r = *(const float4*)(xp + pi*256);
      dst[pi*4+0]=r.x; dst[pi*4+1]=r.y; dst[pi*4+2]=r.z; dst[pi*4+3]=r.w;
    }
  }
  __syncthreads();
  if (tid < 128){ // phase B: thread (s, h8): scores + softmax -> attnT
    const int s = tid >> 3, h8 = tid & 7;
    const int hh = hq*8 + h8;
    const float* qrow = Cbig + (size_t)(1024+hh)*CN;
    const float* prow = &patchP[s*260];
    float sc[16];
    #pragma unroll
    for (int v=0; v<16; ++v){
      float a = qrow[256+v];
      const float* qp = qrow + v*16;
      const float* pp = prow + v*16;
      #pragma unroll
      for (int k=0;k<16;++k) a += qp[k]*pp[k];
      sc[v] = a;
    }
    float mx = sc[0];
    #pragma unroll
    for (int v=1;v<16;++v) mx = fmaxf(mx, sc[v]);
    float sum = 0.f;
    #pragma unroll
    for (int v=0;v<16;++v){ sc[v] = __expf(sc[v]-mx); sum += sc[v]; }
    float inv = 1.f/sum;
    float* arow = &attnT[h8*320 + s*20];
    #pragma unroll
    for (int v=0;v<16;++v) arow[v] = sc[v]*inv;
  }
  __syncthreads();
  // phase C
  const int wave = tid >> 6, lane = tid & 63;
  const int m = lane & 15, quad = lane >> 4;
  const int l0 = sg*16;
  #pragma unroll
  for (int it=0; it<2; ++it){
    const int h8 = wave*2 + it;
    const int hh = hq*8 + h8;
    const float* at = &attnT[h8*320];
    f32x4 acc[4];
    #pragma unroll
    for (int dt=0;dt<4;++dt) acc[dt] = (f32x4){0.f,0.f,0.f,0.f};
    #pragma unroll
    for (int vp=0; vp<8; ++vp){
      const int v = vp*2 + (quad>>1);
      const int k8 = (quad&1)*8;
      const float aw = at[m*20 + v];
      const float* pp = &patchP[m*260 + v*16 + k8];
      BF8 af;
      #pragma unroll
      for (int j=0;j<8;++j) af.s[j] = f2bu(aw*pp[j]);
      #pragma unroll
      for (int dt=0; dt<4; ++dt){
        const int d = hh*64 + dt*16 + m;
        const bf16x8 bf = *(const bf16x8*)(Wb2 + (size_t)d*256 + vp*32 + quad*8);
        acc[dt] = __builtin_amdgcn_mfma_f32_16x16x32_bf16(af.v, bf, acc[dt], 0,0,0);
      }
    }
    // scalar c0-term (R6 semantics) + P2 + store
    #pragma unroll
    for (int dt=0; dt<4; ++dt){
      const int d = hh*64 + dt*16 + m;
      const float* c0p = Cbig + (size_t)d*CN + 256;
      float c0v[16];
      #pragma unroll
      for (int j=0;j<4;++j){
        float4 t = *(const float4*)(c0p + 4*j);
        c0v[4*j+0]=t.x; c0v[4*j+1]=t.y; c0v[4*j+2]=t.z; c0v[4*j+3]=t.w;
      }
      const float bvd = bv[d];
      #pragma unroll
      for (int r=0;r<4;++r){
        const int s = quad*4 + r;
        float dot = bvd;   // sum_v attn = 1
        const float* as_ = at + s*20;
        #pragma unroll
        for (int v=0;v<16;++v) dot += as_[v]*c0v[v];
        ctx[(size_t)(l0+s)*D_ + d] = f2bu(acc[dt][r] + dot + P2[(size_t)(l0+s)*D_ + d]);
      }
    }
  }
}

// ---------------------------------------------------------------------------
extern "C" void kernel_launch(void* const* d_in, const int* in_sizes, int n_in,
                              void* d_out, int out_size, void* d_ws, size_t ws_size,
                              hipStream_t stream){
  const float* x      = (const float*)d_in[0];
  const float* proj_w = (const float*)d_in[1];
  const float* proj_b = (const float*)d_in[2];
  const float* ce     = (const float*)d_in[3];
  const float* pe     = (const float*)d_in[4];
  const float* cq     = (const float*)d_in[5];
  const float* wq     = (const float*)d_in[6];
  const float* wk     = (const float*)d_in[7];
  const float* wv     = (const float*)d_in[8];
  const float* bq     = (const float*)d_in[9];
  // bk (d_in[10]) cancels in softmax
  const float* bv     = (const float*)d_in[11];
  const float* wo     = (const float*)d_in[12];
  const float* bo     = (const float*)d_in[13];
  float* out = (float*)d_out;

  // workspace — peak 8,470,912 B (< proven 9,589,760)
  char* base = (char*)d_ws;
  float*          q    = (float*)(base);                            // 4 KB
  float*          qwk  = (float*)(base + 4096);                     // 64 KB -> 69,632
  unsigned short* ctxb = (unsigned short*)(base + 69632);           // [2048][1024] bf16 (region A, 4 MB)
  unsigned short* Ab   = (unsigned short*)(base + 69632);           // [1152][1024] bf16 (overlaps ctxb; dead before fused6)
  unsigned short* Btb  = (unsigned short*)(base + 69632 + 2359296); // [384][1024] bf16 (overlaps ctxb)
  float*          Cbig = (float*)(base + 4263936);                  // [1040][384] f32 -> 5,861,376
  unsigned short* wo_b = (unsigned short*)(base + 5861376);         // [1024][1024] bf16 -> 7,958,528
  unsigned short* Wb2  = (unsigned short*)(base + 7958528);         // [1024][256] bf16 -> 8,470,912
  // staged in d_out: peb (bf16 pe) in out[0] region, dead after P2-gemm;
  // ctxb1 (bf16 ctx b=1) then reuses out[0]; P2 (fp32 pe·wv^T) in out[1] region.
  unsigned short* peb   = (unsigned short*)out;
  unsigned short* ctxb1 = (unsigned short*)out;
  float*          P2    = out + (size_t)L_*D_;

  k_qinit<<<4,   256, 0, stream>>>(bq, q);
  k_q2   <<<256, 256, 0, stream>>>(cq, wq, q);
  k_qwk2 <<<256, 256, 0, stream>>>(q, wk, qwk);
  k_cvt  <<<1024,256, 0, stream>>>(wv, Ab, 1.0f);                       // Ab rows 0..1023 = bf16(wv)
  k_cvt  <<<16,  256, 0, stream>>>(qwk, Ab + (size_t)1024*D_, 0.125f);  // rows 1024..1039 = qwk/8
  k_cvt  <<<1024,256, 0, stream>>>(wo, wo_b, 1.0f);
  k_cvt  <<<2048,256, 0, stream>>>(pe, peb, 1.0f);
  k_tpB  <<<dim3(16,16), 256, 0, stream>>>(proj_w, proj_b, ce, Btb);
  // Cbig = [wv; qwk/8] · [proj_w^T; pb+ce]^T
  k_gemm<false,false><<<dim3(3,17), 256, 0, stream>>>(Ab, Btb, nullptr, Cbig, 1024, CN, 1040);
  k_wprep2<<<256, 256, 0, stream>>>(Cbig, Wb2);
  // P2 = pe · wv^T  (all-bf16 async path; peb dead after this)
  k_gemm<false,false><<<dim3(8,32), 256, 0, stream>>>(peb, Ab, nullptr, P2, 1024, 1024, 2048);
  // fused: both batches, ctx(b=0)->ws, ctx(b=1)->out[0] region
  k_fused6<<<512, 256, 0, stream>>>(x, Cbig, Wb2, bv, P2, ctxb, ctxb1);
  // out[1] first (consumes P2's region ok - P2 dead; reads ctxb1 from out[0])
  k_gemm<false,true><<<dim3(8,32), 256, 0, stream>>>(ctxb1, wo_b, bo, out + (size_t)L_*D_, 1024, 1024, 2048);
  // out[0] last (clobbers ctxb1 - dead)
  k_gemm<false,true><<<dim3(8,32), 256, 0, stream>>>(ctxb,  wo_b, bo, out,                 1024, 1024, 2048);
}

// Round 10
// 226.992 us; speedup vs baseline: 1.4040x; 1.0794x over previous
//
#include <hip/hip_runtime.h>
#include <hip/hip_bf16.h>

using bf16 = __hip_bfloat16;
using bf16x8 = __attribute__((ext_vector_type(8))) short;
using f32x4  = __attribute__((ext_vector_type(4))) float;

__device__ inline unsigned short f2bu(float f){ bf16 h = __float2bfloat16(f); return *(unsigned short*)&h; }
__device__ inline void async_cp16(const void* g, void* l){
  __builtin_amdgcn_global_load_lds((const __attribute__((address_space(1))) void*)g,
                                   (__attribute__((address_space(3))) void*)l, 16, 0, 0);
}
union BF8 { unsigned short s[8]; bf16x8 v; };

constexpr int D_ = 1024, L_ = 2048;
constexpr int CN = 384;   // Cbig row stride (floats)

// ---------------------------------------------------------------------------
// q[e] = bq[e] + sum_d cq[d]*wq[e,d]; grid 16, 4 waves x 16 e each, shuffle-reduce
__global__ __launch_bounds__(256) void k_q3(const float* __restrict__ cq, const float* __restrict__ wq,
                                            const float* __restrict__ bq, float* __restrict__ q){
  const int wave = threadIdx.x >> 6, lane = threadIdx.x & 63;
  float cqv[16];
  #pragma unroll
  for (int k=0;k<16;++k) cqv[k] = cq[lane + 64*k];
  #pragma unroll
  for (int j=0;j<16;++j){
    const int e = blockIdx.x*64 + wave*16 + j;
    const float* wr = wq + (size_t)e*D_;
    float p = 0.f;
    #pragma unroll
    for (int k=0;k<16;++k) p += cqv[k]*wr[lane + 64*k];
    #pragma unroll
    for (int m=32;m>=1;m>>=1) p += __shfl_xor(p, m, 64);
    if (lane==0) q[e] = p + bq[e];
  }
}

// Ab row 1024+hh, col d = bf16( 0.125 * sum_e q[hh*64+e]*wk[hh*64+e,d] ); grid 256
__global__ __launch_bounds__(256) void k_qwk3(const float* __restrict__ q, const float* __restrict__ wk,
                                              unsigned short* __restrict__ Abq){
  __shared__ float red[4][64];
  const int hh = blockIdx.x >> 4, dq = blockIdx.x & 15;
  const int eg = threadIdx.x >> 6, dl = threadIdx.x & 63;
  const int d = dq*64 + dl;
  float s = 0.f;
  #pragma unroll
  for (int j=0;j<16;++j){
    int e = hh*64 + eg*16 + j;
    s += q[e]*wk[(size_t)e*D_ + d];
  }
  red[eg][dl] = s;
  __syncthreads();
  if (eg==0)
    Abq[(size_t)hh*D_ + d] = f2bu(((red[0][dl]+red[1][dl]) + (red[2][dl]+red[3][dl]))*0.125f);
}

// mega convert: wv->Ab rows 0..1023, wo->wo_b, pe->peb. grid 4096 (block-aligned ranges)
__global__ __launch_bounds__(256) void k_mcvt(const float* __restrict__ wv, const float* __restrict__ wo,
                                              const float* __restrict__ pe, unsigned short* __restrict__ Ab,
                                              unsigned short* __restrict__ wo_b, unsigned short* __restrict__ peb){
  int i = blockIdx.x*256 + threadIdx.x;   // float4-quad index, 1,048,576 total
  const float* src; unsigned short* dst; size_t off;
  if (i < 262144)      { src = wv; dst = Ab;   off = i; }
  else if (i < 524288) { src = wo; dst = wo_b; off = i - 262144; }
  else                 { src = pe; dst = peb;  off = i - 524288; }
  float4 v = *(const float4*)(src + off*4);
  *(ushort4*)(dst + off*4) = make_ushort4(f2bu(v.x), f2bu(v.y), f2bu(v.z), f2bu(v.w));
}

// Build Btb [384][1024] bf16: rows v*16+k = proj_w[v][dd][k] (transposed);
// rows 256+v = proj_b[v]+ce[v]. grid (16 ddchunk, 16 v).
__global__ __launch_bounds__(256) void k_tpB(const float* __restrict__ proj_w, const float* __restrict__ proj_b,
                                             const float* __restrict__ ce, unsigned short* __restrict__ Btb){
  __shared__ float t[64][17];
  const int tid = threadIdx.x;
  const int v = blockIdx.y, dd0 = blockIdx.x*64;
  { const int r = tid >> 2, kq = tid & 3;
    float4 a = *(const float4*)(proj_w + ((size_t)(v*D_ + dd0 + r))*16 + kq*4);
    t[r][kq*4+0]=a.x; t[r][kq*4+1]=a.y; t[r][kq*4+2]=a.z; t[r][kq*4+3]=a.w; }
  __syncthreads();
  { const int k = tid >> 4, c0 = (tid & 15)*4;
    ushort4 o = make_ushort4(f2bu(t[c0+0][k]), f2bu(t[c0+1][k]), f2bu(t[c0+2][k]), f2bu(t[c0+3][k]));
    *(ushort4*)(Btb + (size_t)(v*16+k)*D_ + dd0 + c0) = o; }
  if (tid < 16){
    const int c0 = tid*4;
    float4 pb = *(const float4*)(proj_b + v*D_ + dd0 + c0);
    float4 cc = *(const float4*)(ce     + v*D_ + dd0 + c0);
    ushort4 o = make_ushort4(f2bu(pb.x+cc.x), f2bu(pb.y+cc.y), f2bu(pb.z+cc.z), f2bu(pb.w+cc.w));
    *(ushort4*)(Btb + (size_t)(256+v)*D_ + dd0 + c0) = o;
  }
}

// ---------------------------------------------------------------------------
// GEMM BK=64: C fp32 [M][ldc] = A(bf16)[M][K] * Bt(bf16)[N][K]^T (+bias) (+Wb2 bf16 side-write)
// BM=64, BN=128; 4 waves, wave tile 32x64. LDS slot swizzle: slot k8 = g ^ (row&7)
// (dest stays linear for global_load_lds; source g permuted; reads <=2-way banks).
template<bool BIAS, bool WB2>
__global__ __launch_bounds__(256) void k_gemm64(const unsigned short* __restrict__ A,
                                                const unsigned short* __restrict__ Bt,
                                                const float* __restrict__ bias,
                                                float* __restrict__ C,
                                                unsigned short* __restrict__ W,
                                                int K, int ldc, int Mvalid){
  __shared__ unsigned short As[64*64];
  __shared__ unsigned short Bs[128*64];
  const int tid = threadIdx.x;
  const int wave = tid >> 6, lane = tid & 63;
  const int wm = wave & 1, wn = wave >> 1;
  const int m0 = blockIdx.y*64, n0 = blockIdx.x*128;
  const int lm = lane & 15, kg4 = lane >> 4;
  f32x4 acc[2][4];
  #pragma unroll
  for (int mf=0;mf<2;++mf)
    #pragma unroll
    for (int nf=0;nf<4;++nf)
      acc[mf][nf] = (f32x4){0.f,0.f,0.f,0.f};
  for (int k0=0; k0<K; k0+=64){
    #pragma unroll
    for (int i=0;i<2;++i){
      int idx = i*256 + tid;
      int row = idx >> 3, slotk = idx & 7;
      int g = slotk ^ (row & 7);
      async_cp16(A + (size_t)(m0+row)*K + k0 + g*8, &As[idx*8]);
    }
    #pragma unroll
    for (int i=0;i<4;++i){
      int idx = i*256 + tid;
      int row = idx >> 3, slotk = idx & 7;
      int g = slotk ^ (row & 7);
      async_cp16(Bt + (size_t)(n0+row)*K + k0 + g*8, &Bs[idx*8]);
    }
    __syncthreads();
    #pragma unroll
    for (int c=0;c<2;++c){
      bf16x8 af[2], bfr[4];
      #pragma unroll
      for (int f=0;f<2;++f){
        int row = wm*32 + f*16 + lm;
        af[f] = *(const bf16x8*)(&As[row*64 + (((c*4+kg4) ^ (row&7)))*8]);
      }
      #pragma unroll
      for (int f=0;f<4;++f){
        int colr = wn*64 + f*16 + lm;
        bfr[f] = *(const bf16x8*)(&Bs[colr*64 + (((c*4+kg4) ^ (colr&7)))*8]);
      }
      #pragma unroll
      for (int mf=0;mf<2;++mf)
        #pragma unroll
        for (int nf=0;nf<4;++nf)
          acc[mf][nf] = __builtin_amdgcn_mfma_f32_16x16x32_bf16(af[mf], bfr[nf], acc[mf][nf], 0,0,0);
    }
    __syncthreads();
  }
  #pragma unroll
  for (int nf=0;nf<4;++nf){
    int col = n0 + wn*64 + nf*16 + lm;
    float bval = BIAS ? bias[col] : 0.f;
    #pragma unroll
    for (int mf=0;mf<2;++mf){
      #pragma unroll
      for (int r=0;r<4;++r){
        int row = m0 + wm*32 + mf*16 + kg4*4 + r;
        if (row < Mvalid){
          float v = acc[mf][nf][r];
          C[(size_t)row*ldc + col] = v + bval;
          if (WB2 && row < 1024 && col < 256) W[(size_t)row*256 + col] = f2bu(v);
        }
      }
    }
  }
}

// ---------------------------------------------------------------------------
// fused, both batches in one launch (verified R9 math, unchanged):
// grid 512 = (bb) x (sg 128) x (hq); block: 16 sites x 8 heads, 4 waves.
__global__ __launch_bounds__(256) void k_fused6(const float* __restrict__ x,
                                                const float* __restrict__ Cbig,
                                                const unsigned short* __restrict__ Wb2,
                                                const float* __restrict__ bv,
                                                const float* __restrict__ P2,
                                                unsigned short* __restrict__ ctx0,
                                                unsigned short* __restrict__ ctx1){
  __shared__ float patchP[16*260];   // [s][v*16+k]
  __shared__ float attnT[8*320];     // [h8][s*20+v]
  const int tid = threadIdx.x;
  const int bb = blockIdx.x >> 8;
  const int sg = (blockIdx.x >> 1) & 127;
  const int hq = blockIdx.x & 1;
  unsigned short* ctx = bb ? ctx1 : ctx0;
  { // phase A
    const int s = tid >> 4, v = tid & 15;
    const int l = sg*16 + s;
    const int hi = l >> 6, wi = l & 63;
    const float* xp = x + ((size_t)((bb*16+v)*128 + hi*4)*256 + wi*4);
    float* dst = &patchP[s*260 + v*16];
    #pragma unroll
    for (int pi=0; pi<4; ++pi){
      float4 r = *(const float4*)(xp + pi*256);
      dst[pi*4+0]=r.x; dst[pi*4+1]=r.y; dst[pi*4+2]=r.z; dst[pi*4+3]=r.w;
    }
  }
  __syncthreads();
  if (tid < 128){ // phase B
    const int s = tid >> 3, h8 = tid & 7;
    const int hh = hq*8 + h8;
    const float* qrow = Cbig + (size_t)(1024+hh)*CN;
    const float* prow = &patchP[s*260];
    float sc[16];
    #pragma unroll
    for (int v=0; v<16; ++v){
      float a = qrow[256+v];
      const float* qp = qrow + v*16;
      const float* pp = prow + v*16;
      #pragma unroll
      for (int k=0;k<16;++k) a += qp[k]*pp[k];
      sc[v] = a;
    }
    float mx = sc[0];
    #pragma unroll
    for (int v=1;v<16;++v) mx = fmaxf(mx, sc[v]);
    float sum = 0.f;
    #pragma unroll
    for (int v=0;v<16;++v){ sc[v] = __expf(sc[v]-mx); sum += sc[v]; }
    float inv = 1.f/sum;
    float* arow = &attnT[h8*320 + s*20];
    #pragma unroll
    for (int v=0;v<16;++v) arow[v] = sc[v]*inv;
  }
  __syncthreads();
  // phase C
  const int wave = tid >> 6, lane = tid & 63;
  const int m = lane & 15, quad = lane >> 4;
  const int l0 = sg*16;
  #pragma unroll
  for (int it=0; it<2; ++it){
    const int h8 = wave*2 + it;
    const int hh = hq*8 + h8;
    const float* at = &attnT[h8*320];
    f32x4 acc[4];
    #pragma unroll
    for (int dt=0;dt<4;++dt) acc[dt] = (f32x4){0.f,0.f,0.f,0.f};
    #pragma unroll
    for (int vp=0; vp<8; ++vp){
      const int v = vp*2 + (quad>>1);
      const int k8 = (quad&1)*8;
      const float aw = at[m*20 + v];
      const float* pp = &patchP[m*260 + v*16 + k8];
      BF8 af;
      #pragma unroll
      for (int j=0;j<8;++j) af.s[j] = f2bu(aw*pp[j]);
      #pragma unroll
      for (int dt=0; dt<4; ++dt){
        const int d = hh*64 + dt*16 + m;
        const bf16x8 bf = *(const bf16x8*)(Wb2 + (size_t)d*256 + vp*32 + quad*8);
        acc[dt] = __builtin_amdgcn_mfma_f32_16x16x32_bf16(af.v, bf, acc[dt], 0,0,0);
      }
    }
    #pragma unroll
    for (int dt=0; dt<4; ++dt){
      const int d = hh*64 + dt*16 + m;
      const float* c0p = Cbig + (size_t)d*CN + 256;
      float c0v[16];
      #pragma unroll
      for (int j=0;j<4;++j){
        float4 t = *(const float4*)(c0p + 4*j);
        c0v[4*j+0]=t.x; c0v[4*j+1]=t.y; c0v[4*j+2]=t.z; c0v[4*j+3]=t.w;
      }
      const float bvd = bv[d];
      #pragma unroll
      for (int r=0;r<4;++r){
        const int s = quad*4 + r;
        float dot = bvd;   // sum_v attn = 1
        const float* as_ = at + s*20;
        #pragma unroll
        for (int v=0;v<16;++v) dot += as_[v]*c0v[v];
        ctx[(size_t)(l0+s)*D_ + d] = f2bu(acc[dt][r] + dot + P2[(size_t)(l0+s)*D_ + d]);
      }
    }
  }
}

// ---------------------------------------------------------------------------
extern "C" void kernel_launch(void* const* d_in, const int* in_sizes, int n_in,
                              void* d_out, int out_size, void* d_ws, size_t ws_size,
                              hipStream_t stream){
  const float* x      = (const float*)d_in[0];
  const float* proj_w = (const float*)d_in[1];
  const float* proj_b = (const float*)d_in[2];
  const float* ce     = (const float*)d_in[3];
  const float* pe     = (const float*)d_in[4];
  const float* cq     = (const float*)d_in[5];
  const float* wq     = (const float*)d_in[6];
  const float* wk     = (const float*)d_in[7];
  const float* wv     = (const float*)d_in[8];
  const float* bq     = (const float*)d_in[9];
  // bk (d_in[10]) cancels in softmax
  const float* bv     = (const float*)d_in[11];
  const float* wo     = (const float*)d_in[12];
  const float* bo     = (const float*)d_in[13];
  float* out = (float*)d_out;

  // workspace — peak 8,470,912 B (< proven 9,589,760)
  char* base = (char*)d_ws;
  float*          q    = (float*)(base);                            // 4 KB
  unsigned short* ctxb = (unsigned short*)(base + 69632);           // [2048][1024] bf16 (region A)
  unsigned short* Ab   = (unsigned short*)(base + 69632);           // [1152][1024] bf16 (overlaps ctxb; dead before fused6)
  unsigned short* Btb  = (unsigned short*)(base + 69632 + 2359296); // [384][1024] bf16 (overlaps ctxb)
  float*          Cbig = (float*)(base + 4263936);                  // [1040][384] f32 -> 5,861,376
  unsigned short* wo_b = (unsigned short*)(base + 5861376);         // [1024][1024] bf16 -> 7,958,528
  unsigned short* Wb2  = (unsigned short*)(base + 7958528);         // [1024][256] bf16 -> 8,470,912
  // staged in d_out: peb (bf16 pe) in out[0], dead after P2-gemm; ctxb1 reuses out[0]; P2 in out[1].
  unsigned short* peb   = (unsigned short*)out;
  unsigned short* ctxb1 = (unsigned short*)out;
  float*          P2    = out + (size_t)L_*D_;

  k_q3   <<<16,  256, 0, stream>>>(cq, wq, bq, q);
  k_qwk3 <<<256, 256, 0, stream>>>(q, wk, Ab + (size_t)1024*D_);     // Ab rows 1024..1039 = qwk/8
  k_mcvt <<<4096,256, 0, stream>>>(wv, wo, pe, Ab, wo_b, peb);       // Ab rows 0..1023 = bf16(wv)
  k_tpB  <<<dim3(16,16), 256, 0, stream>>>(proj_w, proj_b, ce, Btb);
  // Cbig = [wv; qwk/8] · [proj_w^T; pb+ce]^T ; epilogue also writes Wb2
  k_gemm64<false,true><<<dim3(3,17), 256, 0, stream>>>(Ab, Btb, nullptr, Cbig, Wb2, 1024, CN, 1040);
  // P2 = pe · wv^T
  k_gemm64<false,false><<<dim3(8,32), 256, 0, stream>>>(peb, Ab, nullptr, P2, nullptr, 1024, 1024, 2048);
  // fused: both batches, ctx(b=0)->ws, ctx(b=1)->out[0] region
  k_fused6<<<512, 256, 0, stream>>>(x, Cbig, Wb2, bv, P2, ctxb, ctxb1);
  // out[1] first (P2 dead; reads ctxb1 from out[0]); out[0] last (clobbers dead ctxb1)
  k_gemm64<true,false><<<dim3(8,32), 256, 0, stream>>>(ctxb1, wo_b, bo, out + (size_t)L_*D_, nullptr, 1024, 1024, 2048);
  k_gemm64<true,false><<<dim3(8,32), 256, 0, stream>>>(ctxb,  wo_b, bo, out,                 nullptr, 1024, 1024, 2048);
}

// Round 11
// 195.292 us; speedup vs baseline: 1.6319x; 1.1623x over previous
//
#include <hip/hip_runtime.h>
#include <hip/hip_bf16.h>

using bf16 = __hip_bfloat16;
using bf16x8 = __attribute__((ext_vector_type(8))) short;
using f32x4  = __attribute__((ext_vector_type(4))) float;

__device__ inline unsigned short f2bu(float f){ bf16 h = __float2bfloat16(f); return *(unsigned short*)&h; }
__device__ inline void async_cp16(const void* g, void* l){
  __builtin_amdgcn_global_load_lds((const __attribute__((address_space(1))) void*)g,
                                   (__attribute__((address_space(3))) void*)l, 16, 0, 0);
}
union BF8 { unsigned short s[8]; bf16x8 v; };

constexpr int D_ = 1024, L_ = 2048;
constexpr int CN = 384;   // Cbig row stride (floats)

// ---------------------------------------------------------------------------
// merged prep: blocks 0..4095 = mcvt (wv->Ab, wo->wo_b, pe->peb);
// 4096..4351 = tpB (proj_w/proj_b/ce -> Btb); 4352..4367 = q3 (cq,wq,bq -> q)
__global__ __launch_bounds__(256) void k_prep(const float* __restrict__ wv, const float* __restrict__ wo,
                                              const float* __restrict__ pe, const float* __restrict__ proj_w,
                                              const float* __restrict__ proj_b, const float* __restrict__ ce,
                                              const float* __restrict__ cq, const float* __restrict__ wq,
                                              const float* __restrict__ bq,
                                              unsigned short* __restrict__ Ab, unsigned short* __restrict__ wo_b,
                                              unsigned short* __restrict__ peb, unsigned short* __restrict__ Btb,
                                              float* __restrict__ q){
  __shared__ float t[64][17];
  const int blk = blockIdx.x;
  const int tid = threadIdx.x;
  if (blk < 4096){           // ---- mcvt: float4-quad i
    int i = blk*256 + tid;
    const float* src; unsigned short* dst; size_t off;
    if (i < 262144)      { src = wv; dst = Ab;   off = i; }
    else if (i < 524288) { src = wo; dst = wo_b; off = i - 262144; }
    else                 { src = pe; dst = peb;  off = i - 524288; }
    float4 v = *(const float4*)(src + off*4);
    *(ushort4*)(dst + off*4) = make_ushort4(f2bu(v.x), f2bu(v.y), f2bu(v.z), f2bu(v.w));
  } else if (blk < 4352){    // ---- tpB
    const int r_ = blk - 4096;
    const int v = r_ >> 4, dd0 = (r_ & 15)*64;
    { const int r = tid >> 2, kq = tid & 3;
      float4 a = *(const float4*)(proj_w + ((size_t)(v*D_ + dd0 + r))*16 + kq*4);
      t[r][kq*4+0]=a.x; t[r][kq*4+1]=a.y; t[r][kq*4+2]=a.z; t[r][kq*4+3]=a.w; }
    __syncthreads();
    { const int k = tid >> 4, c0 = (tid & 15)*4;
      ushort4 o = make_ushort4(f2bu(t[c0+0][k]), f2bu(t[c0+1][k]), f2bu(t[c0+2][k]), f2bu(t[c0+3][k]));
      *(ushort4*)(Btb + (size_t)(v*16+k)*D_ + dd0 + c0) = o; }
    if (tid < 16){
      const int c0 = tid*4;
      float4 pb = *(const float4*)(proj_b + v*D_ + dd0 + c0);
      float4 cc = *(const float4*)(ce     + v*D_ + dd0 + c0);
      ushort4 o = make_ushort4(f2bu(pb.x+cc.x), f2bu(pb.y+cc.y), f2bu(pb.z+cc.z), f2bu(pb.w+cc.w));
      *(ushort4*)(Btb + (size_t)(256+v)*D_ + dd0 + c0) = o;
    }
  } else {                   // ---- q3
    const int bq_ = blk - 4352;
    const int wave = tid >> 6, lane = tid & 63;
    float cqv[16];
    #pragma unroll
    for (int k=0;k<16;++k) cqv[k] = cq[lane + 64*k];
    #pragma unroll
    for (int j=0;j<16;++j){
      const int e = bq_*64 + wave*16 + j;
      const float* wr = wq + (size_t)e*D_;
      float p = 0.f;
      #pragma unroll
      for (int k=0;k<16;++k) p += cqv[k]*wr[lane + 64*k];
      #pragma unroll
      for (int m=32;m>=1;m>>=1) p += __shfl_xor(p, m, 64);
      if (lane==0) q[e] = p + bq[e];
    }
  }
}

// Ab row 1024+hh, col d = bf16( 0.125 * sum_e q[hh*64+e]*wk[hh*64+e,d] ); grid 256
__global__ __launch_bounds__(256) void k_qwk3(const float* __restrict__ q, const float* __restrict__ wk,
                                              unsigned short* __restrict__ Abq){
  __shared__ float red[4][64];
  const int hh = blockIdx.x >> 4, dq = blockIdx.x & 15;
  const int eg = threadIdx.x >> 6, dl = threadIdx.x & 63;
  const int d = dq*64 + dl;
  float s = 0.f;
  #pragma unroll
  for (int j=0;j<16;++j){
    int e = hh*64 + eg*16 + j;
    s += q[e]*wk[(size_t)e*D_ + d];
  }
  red[eg][dl] = s;
  __syncthreads();
  if (eg==0)
    Abq[(size_t)hh*D_ + d] = f2bu(((red[0][dl]+red[1][dl]) + (red[2][dl]+red[3][dl]))*0.125f);
}

// ---------------------------------------------------------------------------
// GEMM bodies (BK=64, async 16B staging, XOR slot swizzle ^(row&7); reads <=2-way banks)
__device__ inline void gemm64_body(unsigned short* As, unsigned short* Bs,
                                   const unsigned short* __restrict__ A, const unsigned short* __restrict__ Bt,
                                   float* __restrict__ C, unsigned short* __restrict__ W,
                                   int m0, int n0, int K, int ldc, int Mvalid){
  const int tid = threadIdx.x;
  const int wave = tid >> 6, lane = tid & 63;
  const int wm = wave & 1, wn = wave >> 1;
  const int lm = lane & 15, kg4 = lane >> 4;
  f32x4 acc[2][4];
  #pragma unroll
  for (int mf=0;mf<2;++mf)
    #pragma unroll
    for (int nf=0;nf<4;++nf) acc[mf][nf] = (f32x4){0.f,0.f,0.f,0.f};
  for (int k0=0; k0<K; k0+=64){
    #pragma unroll
    for (int i=0;i<2;++i){
      int idx = i*256 + tid;
      int row = idx >> 3, g = (idx & 7) ^ (row & 7);
      async_cp16(A + (size_t)(m0+row)*K + k0 + g*8, &As[idx*8]);
    }
    #pragma unroll
    for (int i=0;i<4;++i){
      int idx = i*256 + tid;
      int row = idx >> 3, g = (idx & 7) ^ (row & 7);
      async_cp16(Bt + (size_t)(n0+row)*K + k0 + g*8, &Bs[idx*8]);
    }
    __syncthreads();
    #pragma unroll
    for (int c=0;c<2;++c){
      bf16x8 af[2], bfr[4];
      #pragma unroll
      for (int f=0;f<2;++f){
        int row = wm*32 + f*16 + lm;
        af[f] = *(const bf16x8*)(&As[row*64 + (((c*4+kg4) ^ (row&7)))*8]);
      }
      #pragma unroll
      for (int f=0;f<4;++f){
        int colr = wn*64 + f*16 + lm;
        bfr[f] = *(const bf16x8*)(&Bs[colr*64 + (((c*4+kg4) ^ (colr&7)))*8]);
      }
      #pragma unroll
      for (int mf=0;mf<2;++mf)
        #pragma unroll
        for (int nf=0;nf<4;++nf)
          acc[mf][nf] = __builtin_amdgcn_mfma_f32_16x16x32_bf16(af[mf], bfr[nf], acc[mf][nf], 0,0,0);
    }
    __syncthreads();
  }
  #pragma unroll
  for (int nf=0;nf<4;++nf){
    int col = n0 + wn*64 + nf*16 + lm;
    #pragma unroll
    for (int mf=0;mf<2;++mf){
      #pragma unroll
      for (int r=0;r<4;++r){
        int row = m0 + wm*32 + mf*16 + kg4*4 + r;
        if (row < Mvalid){
          float v = acc[mf][nf][r];
          C[(size_t)row*ldc + col] = v;
          if (row < 1024 && col < 256) W[(size_t)row*256 + col] = f2bu(v);
        }
      }
    }
  }
}

template<bool BIAS>
__device__ inline void gemm128_body(unsigned short* As, unsigned short* Bs,
                                    const unsigned short* __restrict__ A, const unsigned short* __restrict__ Bt,
                                    const float* __restrict__ bias, float* __restrict__ C,
                                    int m0, int n0, int K, int ldc){
  const int tid = threadIdx.x;
  const int wave = tid >> 6, lane = tid & 63;
  const int wm = wave & 1, wn = wave >> 1;
  const int lm = lane & 15, kg4 = lane >> 4;
  f32x4 acc[4][4];
  #pragma unroll
  for (int mf=0;mf<4;++mf)
    #pragma unroll
    for (int nf=0;nf<4;++nf) acc[mf][nf] = (f32x4){0.f,0.f,0.f,0.f};
  for (int k0=0; k0<K; k0+=64){
    #pragma unroll
    for (int i=0;i<4;++i){
      int idx = i*256 + tid;
      int row = idx >> 3, g = (idx & 7) ^ (row & 7);
      async_cp16(A + (size_t)(m0+row)*K + k0 + g*8, &As[idx*8]);
    }
    #pragma unroll
    for (int i=0;i<4;++i){
      int idx = i*256 + tid;
      int row = idx >> 3, g = (idx & 7) ^ (row & 7);
      async_cp16(Bt + (size_t)(n0+row)*K + k0 + g*8, &Bs[idx*8]);
    }
    __syncthreads();
    #pragma unroll
    for (int c=0;c<2;++c){
      bf16x8 af[4], bfr[4];
      #pragma unroll
      for (int f=0;f<4;++f){
        int row = wm*64 + f*16 + lm;
        af[f] = *(const bf16x8*)(&As[row*64 + (((c*4+kg4) ^ (row&7)))*8]);
      }
      #pragma unroll
      for (int f=0;f<4;++f){
        int colr = wn*64 + f*16 + lm;
        bfr[f] = *(const bf16x8*)(&Bs[colr*64 + (((c*4+kg4) ^ (colr&7)))*8]);
      }
      #pragma unroll
      for (int mf=0;mf<4;++mf)
        #pragma unroll
        for (int nf=0;nf<4;++nf)
          acc[mf][nf] = __builtin_amdgcn_mfma_f32_16x16x32_bf16(af[mf], bfr[nf], acc[mf][nf], 0,0,0);
    }
    __syncthreads();
  }
  #pragma unroll
  for (int nf=0;nf<4;++nf){
    int col = n0 + wn*64 + nf*16 + lm;
    float bval = BIAS ? bias[col] : 0.f;
    #pragma unroll
    for (int mf=0;mf<4;++mf){
      #pragma unroll
      for (int r=0;r<4;++r){
        int row = m0 + wm*64 + mf*16 + kg4*4 + r;
        C[(size_t)row*ldc + col] = acc[mf][nf][r] + bval;
      }
    }
  }
}

// merged: blocks 0..50 = Cbig GEMM (+Wb2 side-write); 51..178 = P2 GEMM
__global__ __launch_bounds__(256) void k_gemmCP(const unsigned short* __restrict__ Ab,
                                                const unsigned short* __restrict__ Btb,
                                                const unsigned short* __restrict__ peb,
                                                float* __restrict__ Cbig, unsigned short* __restrict__ Wb2,
                                                float* __restrict__ P2){
  __shared__ unsigned short As[128*64];
  __shared__ unsigned short Bs[128*64];
  if (blockIdx.x < 51){
    int bx = blockIdx.x % 3, by = blockIdx.x / 3;
    gemm64_body(As, Bs, Ab, Btb, Cbig, Wb2, by*64, bx*128, 1024, CN, 1040);
  } else {
    int b = blockIdx.x - 51;
    int bx = b & 7, by = b >> 3;
    gemm128_body<false>(As, Bs, peb, Ab, nullptr, P2, by*128, bx*128, 1024, 1024);
  }
}

// out GEMM: out[M=4096][1024] = ctxF·wo_b^T + bo ; grid (8,32)
__global__ __launch_bounds__(256) void k_gemmOut(const unsigned short* __restrict__ ctxF,
                                                 const unsigned short* __restrict__ wo_b,
                                                 const float* __restrict__ bo, float* __restrict__ C){
  __shared__ unsigned short As[128*64];
  __shared__ unsigned short Bs[128*64];
  gemm128_body<true>(As, Bs, ctxF, wo_b, bo, C, blockIdx.y*128, blockIdx.x*128, 1024, 1024);
}

// ---------------------------------------------------------------------------
// fused, both batches (verified R8/R9/R10 math, unchanged): grid 512 = (bb)x(sg 128)x(hq)
__global__ __launch_bounds__(256) void k_fused6(const float* __restrict__ x,
                                                const float* __restrict__ Cbig,
                                                const unsigned short* __restrict__ Wb2,
                                                const float* __restrict__ bv,
                                                const float* __restrict__ P2,
                                                unsigned short* __restrict__ ctxF){
  __shared__ float patchP[16*260];   // [s][v*16+k]
  __shared__ float attnT[8*320];     // [h8][s*20+v]
  const int tid = threadIdx.x;
  const int bb = blockIdx.x >> 8;
  const int sg = (blockIdx.x >> 1) & 127;
  const int hq = blockIdx.x & 1;
  unsigned short* ctx = ctxF + (size_t)bb*L_*D_;
  { // phase A
    const int s = tid >> 4, v = tid & 15;
    const int l = sg*16 + s;
    const int hi = l >> 6, wi = l & 63;
    const float* xp = x + ((size_t)((bb*16+v)*128 + hi*4)*256 + wi*4);
    float* dst = &patchP[s*260 + v*16];
    #pragma unroll
    for (int pi=0; pi<4; ++pi){
      float4 r = *(const float4*)(xp + pi*256);
      dst[pi*4+0]=r.x; dst[pi*4+1]=r.y; dst[pi*4+2]=r.z; dst[pi*4+3]=r.w;
    }
  }
  __syncthreads();
  if (tid < 128){ // phase B
    const int s = tid >> 3, h8 = tid & 7;
    const int hh = hq*8 + h8;
    const float* qrow = Cbig + (size_t)(1024+hh)*CN;
    const float* prow = &patchP[s*260];
    float sc[16];
    #pragma unroll
    for (int v=0; v<16; ++v){
      float a = qrow[256+v];
      const float* qp = qrow + v*16;
      const float* pp = prow + v*16;
      #pragma unroll
      for (int k=0;k<16;++k) a += qp[k]*pp[k];
      sc[v] = a;
    }
    float mx = sc[0];
    #pragma unroll
    for (int v=1;v<16;++v) mx = fmaxf(mx, sc[v]);
    float sum = 0.f;
    #pragma unroll
    for (int v=0;v<16;++v){ sc[v] = __expf(sc[v]-mx); sum += sc[v]; }
    float inv = 1.f/sum;
    float* arow = &attnT[h8*320 + s*20];
    #pragma unroll
    for (int v=0;v<16;++v) arow[v] = sc[v]*inv;
  }
  __syncthreads();
  // phase C
  const int wave = tid >> 6, lane = tid & 63;
  const int m = lane & 15, quad = lane >> 4;
  const int l0 = sg*16;
  #pragma unroll
  for (int it=0; it<2; ++it){
    const int h8 = wave*2 + it;
    const int hh = hq*8 + h8;
    const float* at = &attnT[h8*320];
    f32x4 acc[4];
    #pragma unroll
    for (int dt=0;dt<4;++dt) acc[dt] = (f32x4){0.f,0.f,0.f,0.f};
    #pragma unroll
    for (int vp=0; vp<8; ++vp){
      const int v = vp*2 + (quad>>1);
      const int k8 = (quad&1)*8;
      const float aw = at[m*20 + v];
      const float* pp = &patchP[m*260 + v*16 + k8];
      BF8 af;
      #pragma unroll
      for (int j=0;j<8;++j) af.s[j] = f2bu(aw*pp[j]);
      #pragma unroll
      for (int dt=0; dt<4; ++dt){
        const int d = hh*64 + dt*16 + m;
        const bf16x8 bf = *(const bf16x8*)(Wb2 + (size_t)d*256 + vp*32 + quad*8);
        acc[dt] = __builtin_amdgcn_mfma_f32_16x16x32_bf16(af.v, bf, acc[dt], 0,0,0);
      }
    }
    #pragma unroll
    for (int dt=0; dt<4; ++dt){
      const int d = hh*64 + dt*16 + m;
      const float* c0p = Cbig + (size_t)d*CN + 256;
      float c0v[16];
      #pragma unroll
      for (int j=0;j<4;++j){
        float4 t = *(const float4*)(c0p + 4*j);
        c0v[4*j+0]=t.x; c0v[4*j+1]=t.y; c0v[4*j+2]=t.z; c0v[4*j+3]=t.w;
      }
      const float bvd = bv[d];
      #pragma unroll
      for (int r=0;r<4;++r){
        const int s = quad*4 + r;
        float dot = bvd;   // sum_v attn = 1
        const float* as_ = at + s*20;
        #pragma unroll
        for (int v=0;v<16;++v) dot += as_[v]*c0v[v];
        ctx[(size_t)(l0+s)*D_ + d] = f2bu(acc[dt][r] + dot + P2[(size_t)(l0+s)*D_ + d]);
      }
    }
  }
}

// ---------------------------------------------------------------------------
extern "C" void kernel_launch(void* const* d_in, const int* in_sizes, int n_in,
                              void* d_out, int out_size, void* d_ws, size_t ws_size,
                              hipStream_t stream){
  const float* x      = (const float*)d_in[0];
  const float* proj_w = (const float*)d_in[1];
  const float* proj_b = (const float*)d_in[2];
  const float* ce     = (const float*)d_in[3];
  const float* pe     = (const float*)d_in[4];
  const float* cq     = (const float*)d_in[5];
  const float* wq     = (const float*)d_in[6];
  const float* wk     = (const float*)d_in[7];
  const float* wv     = (const float*)d_in[8];
  const float* bq     = (const float*)d_in[9];
  // bk (d_in[10]) cancels in softmax
  const float* bv     = (const float*)d_in[11];
  const float* wo     = (const float*)d_in[12];
  const float* bo     = (const float*)d_in[13];
  float* out = (float*)d_out;

  // workspace — flat layout, ~28.3 MB used (ws_size ≈ 268 MB per R10 poison-fill evidence)
  char* base = (char*)d_ws;
  float*          q    = (float*)(base);                       // 4 KB
  unsigned short* Ab   = (unsigned short*)(base + 4096);       // [1152][1024] bf16 -> 2,363,392
  unsigned short* Btb  = (unsigned short*)(base + 2363392);    // [384][1024] bf16 -> 3,149,824
  float*          Cbig = (float*)(base + 3149824);             // [1040][384] f32 -> 4,747,264
  unsigned short* wo_b = (unsigned short*)(base + 4747264);    // [1024][1024] bf16 -> 6,844,416
  unsigned short* Wb2  = (unsigned short*)(base + 6844416);    // [1024][256] bf16 -> 7,368,704
  unsigned short* peb  = (unsigned short*)(base + 7368704);    // [2048][1024] bf16 -> 11,562,  (4 MB)
  float*          P2   = (float*)(base + 11563008);            // [2048][1024] f32 -> 19,951,616
  unsigned short* ctxF = (unsigned short*)(base + 19951616);   // [4096][1024] bf16 -> 28,340,224

  // 1) prep: converts + transposes + q   (mcvt | tpB | q3)
  k_prep<<<4368, 256, 0, stream>>>(wv, wo, pe, proj_w, proj_b, ce, cq, wq, bq,
                                   Ab, wo_b, peb, Btb, q);
  // 2) qwk -> Ab rows 1024..1039
  k_qwk3<<<256, 256, 0, stream>>>(q, wk, Ab + (size_t)1024*D_);
  // 3) Cbig = [wv; qwk/8]·[proj_w^T; pb+ce]^T (+Wb2)  ||  P2 = pe·wv^T
  k_gemmCP<<<179, 256, 0, stream>>>(Ab, Btb, peb, Cbig, Wb2, P2);
  // 4) fused attention -> ctxF (both batches)
  k_fused6<<<512, 256, 0, stream>>>(x, Cbig, Wb2, bv, P2, ctxF);
  // 5) out = ctxF·wo^T + bo   (M=4096)
  k_gemmOut<<<dim3(8,32), 256, 0, stream>>>(ctxF, wo_b, bo, out);
}

// Round 12
// 190.042 us; speedup vs baseline: 1.6770x; 1.0276x over previous
//
#include <hip/hip_runtime.h>
#include <hip/hip_bf16.h>

using bf16 = __hip_bfloat16;
using bf16x8 = __attribute__((ext_vector_type(8))) short;
using f32x4  = __attribute__((ext_vector_type(4))) float;

__device__ inline unsigned short f2bu(float f){ bf16 h = __float2bfloat16(f); return *(unsigned short*)&h; }
__device__ inline void async_cp16(const void* g, void* l){
  __builtin_amdgcn_global_load_lds((const __attribute__((address_space(1))) void*)g,
                                   (__attribute__((address_space(3))) void*)l, 16, 0, 0);
}
union BF8 { unsigned short s[8]; bf16x8 v; };

constexpr int D_ = 1024, L_ = 2048;
constexpr int CN = 384;   // Cbig row stride (floats)

// ---------------------------------------------------------------------------
// merged prep: blocks 0..2047 = mcvt (wv->Ab rows 0..1023, wo->wo_b);
// 2048..2303 = tpB (proj_w/proj_b/ce -> Btb); 2304..2559 = q+qwk fused -> Ab rows 1024..1039
__global__ __launch_bounds__(256) void k_prep2(const float* __restrict__ wv, const float* __restrict__ wo,
                                               const float* __restrict__ proj_w, const float* __restrict__ proj_b,
                                               const float* __restrict__ ce, const float* __restrict__ cq,
                                               const float* __restrict__ wq, const float* __restrict__ bq,
                                               const float* __restrict__ wk,
                                               unsigned short* __restrict__ Ab, unsigned short* __restrict__ wo_b,
                                               unsigned short* __restrict__ Btb){
  __shared__ float t[64][17];
  __shared__ float qL[64];
  __shared__ float red[4][64];
  const int blk = blockIdx.x;
  const int tid = threadIdx.x;
  if (blk < 2048){           // ---- mcvt
    int i = blk*256 + tid;   // float4-quad index
    const float* src; unsigned short* dst; size_t off;
    if (i < 262144){ src = wv; dst = Ab;   off = i; }
    else           { src = wo; dst = wo_b; off = i - 262144; }
    float4 v = *(const float4*)(src + off*4);
    *(ushort4*)(dst + off*4) = make_ushort4(f2bu(v.x), f2bu(v.y), f2bu(v.z), f2bu(v.w));
  } else if (blk < 2304){    // ---- tpB
    const int r_ = blk - 2048;
    const int v = r_ >> 4, dd0 = (r_ & 15)*64;
    { const int r = tid >> 2, kq = tid & 3;
      float4 a = *(const float4*)(proj_w + ((size_t)(v*D_ + dd0 + r))*16 + kq*4);
      t[r][kq*4+0]=a.x; t[r][kq*4+1]=a.y; t[r][kq*4+2]=a.z; t[r][kq*4+3]=a.w; }
    __syncthreads();
    { const int k = tid >> 4, c0 = (tid & 15)*4;
      ushort4 o = make_ushort4(f2bu(t[c0+0][k]), f2bu(t[c0+1][k]), f2bu(t[c0+2][k]), f2bu(t[c0+3][k]));
      *(ushort4*)(Btb + (size_t)(v*16+k)*D_ + dd0 + c0) = o; }
    if (tid < 16){
      const int c0 = tid*4;
      float4 pb = *(const float4*)(proj_b + v*D_ + dd0 + c0);
      float4 cc = *(const float4*)(ce     + v*D_ + dd0 + c0);
      ushort4 o = make_ushort4(f2bu(pb.x+cc.x), f2bu(pb.y+cc.y), f2bu(pb.z+cc.z), f2bu(pb.w+cc.w));
      *(ushort4*)(Btb + (size_t)(256+v)*D_ + dd0 + c0) = o;
    }
  } else {                   // ---- q (in-LDS) + qwk -> Ab row 1024+hh
    const int b = blk - 2304;
    const int hh = b >> 4, dq = b & 15;
    const int wave = tid >> 6, lane = tid & 63;
    { // stage 1: q[e] for e in [hh*64, hh*64+64)  (R11 q3 body)
      float cqv[16];
      #pragma unroll
      for (int k=0;k<16;++k) cqv[k] = cq[lane + 64*k];
      #pragma unroll
      for (int j=0;j<16;++j){
        const int e = hh*64 + wave*16 + j;
        const float* wr = wq + (size_t)e*D_;
        float p = 0.f;
        #pragma unroll
        for (int k=0;k<16;++k) p += cqv[k]*wr[lane + 64*k];
        #pragma unroll
        for (int m=32;m>=1;m>>=1) p += __shfl_xor(p, m, 64);
        if (lane==0) qL[wave*16+j] = p + bq[e];
      }
    }
    __syncthreads();
    { // stage 2: qwk (R11 qwk3 body, q from LDS)
      const int eg = wave, dl = lane;
      const int d = dq*64 + dl;
      float s = 0.f;
      #pragma unroll
      for (int j=0;j<16;++j){
        int e = hh*64 + eg*16 + j;
        s += qL[eg*16+j]*wk[(size_t)e*D_ + d];
      }
      red[eg][dl] = s;
      __syncthreads();
      if (eg==0)
        Ab[(size_t)(1024+hh)*D_ + d] = f2bu(((red[0][dl]+red[1][dl]) + (red[2][dl]+red[3][dl]))*0.125f);
    }
  }
}

// ---------------------------------------------------------------------------
// GEMM body: BM=64, BN=128, BK=64; 4 waves, wave tile 32x64.
// A: bf16-async or fp32-cvt staging (same swizzled layout); B: bf16-async.
// LDS slot swizzle ^(row&7): async dest linear, reads <=2-way banks (R10/R11-verified).
template<bool AFP32, bool BIAS, bool WB2>
__device__ inline void gemm64_body2(unsigned short* As, unsigned short* Bs,
                                    const void* __restrict__ Av, const unsigned short* __restrict__ Bt,
                                    const float* __restrict__ bias, float* __restrict__ C,
                                    unsigned short* __restrict__ W,
                                    int m0, int n0, int K, int ldc, int Mvalid){
  const int tid = threadIdx.x;
  const int wave = tid >> 6, lane = tid & 63;
  const int wm = wave & 1, wn = wave >> 1;
  const int lm = lane & 15, kg4 = lane >> 4;
  const unsigned short* Abf = (const unsigned short*)Av;
  const float* Afp = (const float*)Av;
  f32x4 acc[2][4];
  #pragma unroll
  for (int mf=0;mf<2;++mf)
    #pragma unroll
    for (int nf=0;nf<4;++nf) acc[mf][nf] = (f32x4){0.f,0.f,0.f,0.f};
  for (int k0=0; k0<K; k0+=64){
    #pragma unroll
    for (int i=0;i<2;++i){
      int idx = i*256 + tid;
      int row = idx >> 3, g = (idx & 7) ^ (row & 7);
      if (!AFP32){
        async_cp16(Abf + (size_t)(m0+row)*K + k0 + g*8, &As[idx*8]);
      } else {
        const float* gp = Afp + (size_t)(m0+row)*K + k0 + g*8;
        float4 a0 = *(const float4*)gp, a1 = *(const float4*)(gp+4);
        *(ushort4*)(&As[idx*8])   = make_ushort4(f2bu(a0.x),f2bu(a0.y),f2bu(a0.z),f2bu(a0.w));
        *(ushort4*)(&As[idx*8+4]) = make_ushort4(f2bu(a1.x),f2bu(a1.y),f2bu(a1.z),f2bu(a1.w));
      }
    }
    #pragma unroll
    for (int i=0;i<4;++i){
      int idx = i*256 + tid;
      int row = idx >> 3, g = (idx & 7) ^ (row & 7);
      async_cp16(Bt + (size_t)(n0+row)*K + k0 + g*8, &Bs[idx*8]);
    }
    __syncthreads();
    #pragma unroll
    for (int c=0;c<2;++c){
      bf16x8 af[2], bfr[4];
      #pragma unroll
      for (int f=0;f<2;++f){
        int row = wm*32 + f*16 + lm;
        af[f] = *(const bf16x8*)(&As[row*64 + (((c*4+kg4) ^ (row&7)))*8]);
      }
      #pragma unroll
      for (int f=0;f<4;++f){
        int colr = wn*64 + f*16 + lm;
        bfr[f] = *(const bf16x8*)(&Bs[colr*64 + (((c*4+kg4) ^ (colr&7)))*8]);
      }
      #pragma unroll
      for (int mf=0;mf<2;++mf)
        #pragma unroll
        for (int nf=0;nf<4;++nf)
          acc[mf][nf] = __builtin_amdgcn_mfma_f32_16x16x32_bf16(af[mf], bfr[nf], acc[mf][nf], 0,0,0);
    }
    __syncthreads();
  }
  #pragma unroll
  for (int nf=0;nf<4;++nf){
    int col = n0 + wn*64 + nf*16 + lm;
    float bval = BIAS ? bias[col] : 0.f;
    #pragma unroll
    for (int mf=0;mf<2;++mf){
      #pragma unroll
      for (int r=0;r<4;++r){
        int row = m0 + wm*32 + mf*16 + kg4*4 + r;
        if (row < Mvalid){
          float v = acc[mf][nf][r];
          C[(size_t)row*ldc + col] = v + bval;
          if (WB2 && row < 1024 && col < 256) W[(size_t)row*256 + col] = f2bu(v);
        }
      }
    }
  }
}

// merged: blocks 0..50 = Cbig GEMM (+Wb2 side-write); 51..306 = P2 GEMM (A = pe fp32-staged)
__global__ __launch_bounds__(256) void k_gemmCP2(const unsigned short* __restrict__ Ab,
                                                 const unsigned short* __restrict__ Btb,
                                                 const float* __restrict__ pe,
                                                 float* __restrict__ Cbig, unsigned short* __restrict__ Wb2,
                                                 float* __restrict__ P2){
  __shared__ unsigned short As[64*64];
  __shared__ unsigned short Bs[128*64];
  if (blockIdx.x < 51){
    int bx = blockIdx.x % 3, by = blockIdx.x / 3;
    gemm64_body2<false,false,true>(As, Bs, Ab, Btb, nullptr, Cbig, Wb2, by*64, bx*128, 1024, CN, 1040);
  } else {
    int b = blockIdx.x - 51;
    int bx = b & 7, by = b >> 3;
    gemm64_body2<true,false,false>(As, Bs, pe, Ab, nullptr, P2, nullptr, by*64, bx*128, 1024, 1024, 2048);
  }
}

// out GEMM: out[4096][1024] = ctxF·wo_b^T + bo ; grid (8,64) = 512 blocks
__global__ __launch_bounds__(256) void k_gemmOut(const unsigned short* __restrict__ ctxF,
                                                 const unsigned short* __restrict__ wo_b,
                                                 const float* __restrict__ bo, float* __restrict__ C){
  __shared__ unsigned short As[64*64];
  __shared__ unsigned short Bs[128*64];
  gemm64_body2<false,true,false>(As, Bs, ctxF, wo_b, bo, C, nullptr,
                                 blockIdx.y*64, blockIdx.x*128, 1024, 1024, 4096);
}

// ---------------------------------------------------------------------------
// fused, both batches (verified R8-R11 math, unchanged): grid 512 = (bb)x(sg 128)x(hq)
__global__ __launch_bounds__(256) void k_fused6(const float* __restrict__ x,
                                                const float* __restrict__ Cbig,
                                                const unsigned short* __restrict__ Wb2,
                                                const float* __restrict__ bv,
                                                const float* __restrict__ P2,
                                                unsigned short* __restrict__ ctxF){
  __shared__ float patchP[16*260];   // [s][v*16+k]
  __shared__ float attnT[8*320];     // [h8][s*20+v]
  const int tid = threadIdx.x;
  const int bb = blockIdx.x >> 8;
  const int sg = (blockIdx.x >> 1) & 127;
  const int hq = blockIdx.x & 1;
  unsigned short* ctx = ctxF + (size_t)bb*L_*D_;
  { // phase A
    const int s = tid >> 4, v = tid & 15;
    const int l = sg*16 + s;
    const int hi = l >> 6, wi = l & 63;
    const float* xp = x + ((size_t)((bb*16+v)*128 + hi*4)*256 + wi*4);
    float* dst = &patchP[s*260 + v*16];
    #pragma unroll
    for (int pi=0; pi<4; ++pi){
      float4 r = *(const float4*)(xp + pi*256);
      dst[pi*4+0]=r.x; dst[pi*4+1]=r.y; dst[pi*4+2]=r.z; dst[pi*4+3]=r.w;
    }
  }
  __syncthreads();
  if (tid < 128){ // phase B
    const int s = tid >> 3, h8 = tid & 7;
    const int hh = hq*8 + h8;
    const float* qrow = Cbig + (size_t)(1024+hh)*CN;
    const float* prow = &patchP[s*260];
    float sc[16];
    #pragma unroll
    for (int v=0; v<16; ++v){
      float a = qrow[256+v];
      const float* qp = qrow + v*16;
      const float* pp = prow + v*16;
      #pragma unroll
      for (int k=0;k<16;++k) a += qp[k]*pp[k];
      sc[v] = a;
    }
    float mx = sc[0];
    #pragma unroll
    for (int v=1;v<16;++v) mx = fmaxf(mx, sc[v]);
    float sum = 0.f;
    #pragma unroll
    for (int v=0;v<16;++v){ sc[v] = __expf(sc[v]-mx); sum += sc[v]; }
    float inv = 1.f/sum;
    float* arow = &attnT[h8*320 + s*20];
    #pragma unroll
    for (int v=0;v<16;++v) arow[v] = sc[v]*inv;
  }
  __syncthreads();
  // phase C
  const int wave = tid >> 6, lane = tid & 63;
  const int m = lane & 15, quad = lane >> 4;
  const int l0 = sg*16;
  #pragma unroll
  for (int it=0; it<2; ++it){
    const int h8 = wave*2 + it;
    const int hh = hq*8 + h8;
    const float* at = &attnT[h8*320];
    f32x4 acc[4];
    #pragma unroll
    for (int dt=0;dt<4;++dt) acc[dt] = (f32x4){0.f,0.f,0.f,0.f};
    #pragma unroll
    for (int vp=0; vp<8; ++vp){
      const int v = vp*2 + (quad>>1);
      const int k8 = (quad&1)*8;
      const float aw = at[m*20 + v];
      const float* pp = &patchP[m*260 + v*16 + k8];
      BF8 af;
      #pragma unroll
      for (int j=0;j<8;++j) af.s[j] = f2bu(aw*pp[j]);
      #pragma unroll
      for (int dt=0; dt<4; ++dt){
        const int d = hh*64 + dt*16 + m;
        const bf16x8 bf = *(const bf16x8*)(Wb2 + (size_t)d*256 + vp*32 + quad*8);
        acc[dt] = __builtin_amdgcn_mfma_f32_16x16x32_bf16(af.v, bf, acc[dt], 0,0,0);
      }
    }
    #pragma unroll
    for (int dt=0; dt<4; ++dt){
      const int d = hh*64 + dt*16 + m;
      const float* c0p = Cbig + (size_t)d*CN + 256;
      float c0v[16];
      #pragma unroll
      for (int j=0;j<4;++j){
        float4 t = *(const float4*)(c0p + 4*j);
        c0v[4*j+0]=t.x; c0v[4*j+1]=t.y; c0v[4*j+2]=t.z; c0v[4*j+3]=t.w;
      }
      const float bvd = bv[d];
      #pragma unroll
      for (int r=0;r<4;++r){
        const int s = quad*4 + r;
        float dot = bvd;   // sum_v attn = 1
        const float* as_ = at + s*20;
        #pragma unroll
        for (int v=0;v<16;++v) dot += as_[v]*c0v[v];
        ctx[(size_t)(l0+s)*D_ + d] = f2bu(acc[dt][r] + dot + P2[(size_t)(l0+s)*D_ + d]);
      }
    }
  }
}

// ---------------------------------------------------------------------------
extern "C" void kernel_launch(void* const* d_in, const int* in_sizes, int n_in,
                              void* d_out, int out_size, void* d_ws, size_t ws_size,
                              hipStream_t stream){
  const float* x      = (const float*)d_in[0];
  const float* proj_w = (const float*)d_in[1];
  const float* proj_b = (const float*)d_in[2];
  const float* ce     = (const float*)d_in[3];
  const float* pe     = (const float*)d_in[4];
  const float* cq     = (const float*)d_in[5];
  const float* wq     = (const float*)d_in[6];
  const float* wk     = (const float*)d_in[7];
  const float* wv     = (const float*)d_in[8];
  const float* bq     = (const float*)d_in[9];
  // bk (d_in[10]) cancels in softmax
  const float* bv     = (const float*)d_in[11];
  const float* wo     = (const float*)d_in[12];
  const float* bo     = (const float*)d_in[13];
  float* out = (float*)d_out;

  // workspace — flat, ~24.1 MB used (ws ≈ 268 MB measured via poison-fill WRITE_SIZE)
  char* base = (char*)d_ws;
  unsigned short* Ab   = (unsigned short*)(base);              // [1152][1024] bf16 -> 2,359,296
  unsigned short* Btb  = (unsigned short*)(base + 2359296);    // [384][1024] bf16 -> 3,145,728
  float*          Cbig = (float*)(base + 3145728);             // [1040][384] f32 -> 4,743,168
  unsigned short* wo_b = (unsigned short*)(base + 4743168);    // [1024][1024] bf16 -> 6,840,320
  unsigned short* Wb2  = (unsigned short*)(base + 6840320);    // [1024][256] bf16 -> 7,364,608
  float*          P2   = (float*)(base + 7364608);             // [2048][1024] f32 -> 15,753,216
  unsigned short* ctxF = (unsigned short*)(base + 15753216);   // [4096][1024] bf16 -> 24,141,824

  // 1) prep: mcvt | tpB | q+qwk
  k_prep2<<<2560, 256, 0, stream>>>(wv, wo, proj_w, proj_b, ce, cq, wq, bq, wk, Ab, wo_b, Btb);
  // 2) Cbig (+Wb2)  ||  P2 = pe·wv^T (pe fp32-staged)
  k_gemmCP2<<<307, 256, 0, stream>>>(Ab, Btb, pe, Cbig, Wb2, P2);
  // 3) fused attention -> ctxF (both batches)
  k_fused6<<<512, 256, 0, stream>>>(x, Cbig, Wb2, bv, P2, ctxF);
  // 4) out = ctxF·wo^T + bo
  k_gemmOut<<<dim3(8,64), 256, 0, stream>>>(ctxF, wo_b, bo, out);
}

// Round 13
// 189.179 us; speedup vs baseline: 1.6847x; 1.0046x over previous
//
#include <hip/hip_runtime.h>
#include <hip/hip_bf16.h>

using bf16 = __hip_bfloat16;
using bf16x8 = __attribute__((ext_vector_type(8))) short;
using f32x4  = __attribute__((ext_vector_type(4))) float;

__device__ inline unsigned short f2bu(float f){ bf16 h = __float2bfloat16(f); return *(unsigned short*)&h; }
__device__ inline void async_cp16(const void* g, void* l){
  __builtin_amdgcn_global_load_lds((const __attribute__((address_space(1))) void*)g,
                                   (__attribute__((address_space(3))) void*)l, 16, 0, 0);
}
union BF8 { unsigned short s[8]; bf16x8 v; };

constexpr int D_ = 1024, L_ = 2048;
constexpr int CN = 384;   // Cbig row stride (floats)

// ---------------------------------------------------------------------------
// merged prep: blocks 0..2047 = mcvt (wv->Ab rows 0..1023, wo->wo_b);
// 2048..2303 = tpB (proj_w/proj_b/ce -> Btb); 2304..2559 = q+qwk fused -> Ab rows 1024..1039
__global__ __launch_bounds__(256) void k_prep2(const float* __restrict__ wv, const float* __restrict__ wo,
                                               const float* __restrict__ proj_w, const float* __restrict__ proj_b,
                                               const float* __restrict__ ce, const float* __restrict__ cq,
                                               const float* __restrict__ wq, const float* __restrict__ bq,
                                               const float* __restrict__ wk,
                                               unsigned short* __restrict__ Ab, unsigned short* __restrict__ wo_b,
                                               unsigned short* __restrict__ Btb){
  __shared__ float t[64][17];
  __shared__ float qL[64];
  __shared__ float red[4][64];
  const int blk = blockIdx.x;
  const int tid = threadIdx.x;
  if (blk < 2048){           // ---- mcvt
    int i = blk*256 + tid;   // float4-quad index
    const float* src; unsigned short* dst; size_t off;
    if (i < 262144){ src = wv; dst = Ab;   off = i; }
    else           { src = wo; dst = wo_b; off = i - 262144; }
    float4 v = *(const float4*)(src + off*4);
    *(ushort4*)(dst + off*4) = make_ushort4(f2bu(v.x), f2bu(v.y), f2bu(v.z), f2bu(v.w));
  } else if (blk < 2304){    // ---- tpB
    const int r_ = blk - 2048;
    const int v = r_ >> 4, dd0 = (r_ & 15)*64;
    { const int r = tid >> 2, kq = tid & 3;
      float4 a = *(const float4*)(proj_w + ((size_t)(v*D_ + dd0 + r))*16 + kq*4);
      t[r][kq*4+0]=a.x; t[r][kq*4+1]=a.y; t[r][kq*4+2]=a.z; t[r][kq*4+3]=a.w; }
    __syncthreads();
    { const int k = tid >> 4, c0 = (tid & 15)*4;
      ushort4 o = make_ushort4(f2bu(t[c0+0][k]), f2bu(t[c0+1][k]), f2bu(t[c0+2][k]), f2bu(t[c0+3][k]));
      *(ushort4*)(Btb + (size_t)(v*16+k)*D_ + dd0 + c0) = o; }
    if (tid < 16){
      const int c0 = tid*4;
      float4 pb = *(const float4*)(proj_b + v*D_ + dd0 + c0);
      float4 cc = *(const float4*)(ce     + v*D_ + dd0 + c0);
      ushort4 o = make_ushort4(f2bu(pb.x+cc.x), f2bu(pb.y+cc.y), f2bu(pb.z+cc.z), f2bu(pb.w+cc.w));
      *(ushort4*)(Btb + (size_t)(256+v)*D_ + dd0 + c0) = o;
    }
  } else {                   // ---- q (in-LDS) + qwk -> Ab row 1024+hh
    const int b = blk - 2304;
    const int hh = b >> 4, dq = b & 15;
    const int wave = tid >> 6, lane = tid & 63;
    { // stage 1: q[e] for e in [hh*64, hh*64+64)
      float cqv[16];
      #pragma unroll
      for (int k=0;k<16;++k) cqv[k] = cq[lane + 64*k];
      #pragma unroll
      for (int j=0;j<16;++j){
        const int e = hh*64 + wave*16 + j;
        const float* wr = wq + (size_t)e*D_;
        float p = 0.f;
        #pragma unroll
        for (int k=0;k<16;++k) p += cqv[k]*wr[lane + 64*k];
        #pragma unroll
        for (int m=32;m>=1;m>>=1) p += __shfl_xor(p, m, 64);
        if (lane==0) qL[wave*16+j] = p + bq[e];
      }
    }
    __syncthreads();
    { // stage 2: qwk
      const int eg = wave, dl = lane;
      const int d = dq*64 + dl;
      float s = 0.f;
      #pragma unroll
      for (int j=0;j<16;++j){
        int e = hh*64 + eg*16 + j;
        s += qL[eg*16+j]*wk[(size_t)e*D_ + d];
      }
      red[eg][dl] = s;
      __syncthreads();
      if (eg==0)
        Ab[(size_t)(1024+hh)*D_ + d] = f2bu(((red[0][dl]+red[1][dl]) + (red[2][dl]+red[3][dl]))*0.125f);
    }
  }
}

// ---------------------------------------------------------------------------
// GEMM body: BM=64, BN=128, BK=64; 4 waves, wave tile 32x64.
// LDS slot swizzle ^(row&7): async dest linear, reads <=2-way banks (R10-R12 verified).
template<bool AFP32, bool BIAS, bool WB2>
__device__ inline void gemm64_body2(unsigned short* As, unsigned short* Bs,
                                    const void* __restrict__ Av, const unsigned short* __restrict__ Bt,
                                    const float* __restrict__ bias, float* __restrict__ C,
                                    unsigned short* __restrict__ W,
                                    int m0, int n0, int K, int ldc, int Mvalid){
  const int tid = threadIdx.x;
  const int wave = tid >> 6, lane = tid & 63;
  const int wm = wave & 1, wn = wave >> 1;
  const int lm = lane & 15, kg4 = lane >> 4;
  const unsigned short* Abf = (const unsigned short*)Av;
  const float* Afp = (const float*)Av;
  f32x4 acc[2][4];
  #pragma unroll
  for (int mf=0;mf<2;++mf)
    #pragma unroll
    for (int nf=0;nf<4;++nf) acc[mf][nf] = (f32x4){0.f,0.f,0.f,0.f};
  for (int k0=0; k0<K; k0+=64){
    #pragma unroll
    for (int i=0;i<2;++i){
      int idx = i*256 + tid;
      int row = idx >> 3, g = (idx & 7) ^ (row & 7);
      if (!AFP32){
        async_cp16(Abf + (size_t)(m0+row)*K + k0 + g*8, &As[idx*8]);
      } else {
        const float* gp = Afp + (size_t)(m0+row)*K + k0 + g*8;
        float4 a0 = *(const float4*)gp, a1 = *(const float4*)(gp+4);
        *(ushort4*)(&As[idx*8])   = make_ushort4(f2bu(a0.x),f2bu(a0.y),f2bu(a0.z),f2bu(a0.w));
        *(ushort4*)(&As[idx*8+4]) = make_ushort4(f2bu(a1.x),f2bu(a1.y),f2bu(a1.z),f2bu(a1.w));
      }
    }
    #pragma unroll
    for (int i=0;i<4;++i){
      int idx = i*256 + tid;
      int row = idx >> 3, g = (idx & 7) ^ (row & 7);
      async_cp16(Bt + (size_t)(n0+row)*K + k0 + g*8, &Bs[idx*8]);
    }
    __syncthreads();
    #pragma unroll
    for (int c=0;c<2;++c){
      bf16x8 af[2], bfr[4];
      #pragma unroll
      for (int f=0;f<2;++f){
        int row = wm*32 + f*16 + lm;
        af[f] = *(const bf16x8*)(&As[row*64 + (((c*4+kg4) ^ (row&7)))*8]);
      }
      #pragma unroll
      for (int f=0;f<4;++f){
        int colr = wn*64 + f*16 + lm;
        bfr[f] = *(const bf16x8*)(&Bs[colr*64 + (((c*4+kg4) ^ (colr&7)))*8]);
      }
      #pragma unroll
      for (int mf=0;mf<2;++mf)
        #pragma unroll
        for (int nf=0;nf<4;++nf)
          acc[mf][nf] = __builtin_amdgcn_mfma_f32_16x16x32_bf16(af[mf], bfr[nf], acc[mf][nf], 0,0,0);
    }
    __syncthreads();
  }
  #pragma unroll
  for (int nf=0;nf<4;++nf){
    int col = n0 + wn*64 + nf*16 + lm;
    float bval = BIAS ? bias[col] : 0.f;
    #pragma unroll
    for (int mf=0;mf<2;++mf){
      #pragma unroll
      for (int r=0;r<4;++r){
        int row = m0 + wm*32 + mf*16 + kg4*4 + r;
        if (row < Mvalid){
          float v = acc[mf][nf][r];
          C[(size_t)row*ldc + col] = v + bval;
          if (WB2 && row < 1024 && col < 256) W[(size_t)row*256 + col] = f2bu(v);
        }
      }
    }
  }
}

// merged: blocks 0..50 = Cbig GEMM (+Wb2 side-write); 51..306 = P2 GEMM (A = pe fp32-staged)
__global__ __launch_bounds__(256) void k_gemmCP2(const unsigned short* __restrict__ Ab,
                                                 const unsigned short* __restrict__ Btb,
                                                 const float* __restrict__ pe,
                                                 float* __restrict__ Cbig, unsigned short* __restrict__ Wb2,
                                                 float* __restrict__ P2){
  __shared__ unsigned short As[64*64];
  __shared__ unsigned short Bs[128*64];
  if (blockIdx.x < 51){
    int bx = blockIdx.x % 3, by = blockIdx.x / 3;
    gemm64_body2<false,false,true>(As, Bs, Ab, Btb, nullptr, Cbig, Wb2, by*64, bx*128, 1024, CN, 1040);
  } else {
    int b = blockIdx.x - 51;
    int bx = b & 7, by = b >> 3;
    gemm64_body2<true,false,false>(As, Bs, pe, Ab, nullptr, P2, nullptr, by*64, bx*128, 1024, 1024, 2048);
  }
}

// out GEMM: out[4096][1024] = ctxF·wo_b^T + bo ; grid (8,64) = 512 blocks
__global__ __launch_bounds__(256) void k_gemmOut(const unsigned short* __restrict__ ctxF,
                                                 const unsigned short* __restrict__ wo_b,
                                                 const float* __restrict__ bo, float* __restrict__ C){
  __shared__ unsigned short As[64*64];
  __shared__ unsigned short Bs[128*64];
  gemm64_body2<false,true,false>(As, Bs, ctxF, wo_b, bo, C, nullptr,
                                 blockIdx.y*64, blockIdx.x*128, 1024, 1024, 4096);
}

// ---------------------------------------------------------------------------
// fused v7: grid 1024 = (bb 1b) x (sg 128) x (hqq 2b). Block: 16 sites x 4 heads,
// 4 waves, wave = one head. Phase A coalesced (256 B runs per 16-lane group).
// Per-thread arithmetic identical to verified R8-R12 fused6.
__global__ __launch_bounds__(256) void k_fused7(const float* __restrict__ x,
                                                const float* __restrict__ Cbig,
                                                const unsigned short* __restrict__ Wb2,
                                                const float* __restrict__ bv,
                                                const float* __restrict__ P2,
                                                unsigned short* __restrict__ ctxF){
  __shared__ float patchP[16*260];   // [s][v*16+k]
  __shared__ float attnT[4*320];     // [h4][s*20+v]
  const int tid = threadIdx.x;
  const int bb  = blockIdx.x >> 9;
  const int sg  = (blockIdx.x >> 2) & 127;
  const int hqq = blockIdx.x & 3;
  unsigned short* ctx = ctxF + (size_t)bb*L_*D_;
  const int l0 = sg*16;
  { // phase A: thread (v, u): u = site, coalesced float4 loads
    const int v = tid >> 4, u = tid & 15;
    const int hi = l0 >> 6, wi0 = l0 & 63;
    const float* xp = x + ((size_t)((bb*16+v)*128 + hi*4)*256 + (wi0+u)*4);
    float* dst = &patchP[u*260 + v*16];
    #pragma unroll
    for (int pi=0; pi<4; ++pi){
      float4 r = *(const float4*)(xp + pi*256);
      dst[pi*4+0]=r.x; dst[pi*4+1]=r.y; dst[pi*4+2]=r.z; dst[pi*4+3]=r.w;
    }
  }
  __syncthreads();
  if (tid < 64){ // phase B: thread (s, h4): scores + softmax -> attnT
    const int s = tid >> 2, h4 = tid & 3;
    const int hh = hqq*4 + h4;
    const float* qrow = Cbig + (size_t)(1024+hh)*CN;
    const float* prow = &patchP[s*260];
    float sc[16];
    #pragma unroll
    for (int v=0; v<16; ++v){
      float a = qrow[256+v];
      const float* qp = qrow + v*16;
      const float* pp = prow + v*16;
      #pragma unroll
      for (int k=0;k<16;++k) a += qp[k]*pp[k];
      sc[v] = a;
    }
    float mx = sc[0];
    #pragma unroll
    for (int v=1;v<16;++v) mx = fmaxf(mx, sc[v]);
    float sum = 0.f;
    #pragma unroll
    for (int v=0;v<16;++v){ sc[v] = __expf(sc[v]-mx); sum += sc[v]; }
    float inv = 1.f/sum;
    float* arow = &attnT[h4*320 + s*20];
    #pragma unroll
    for (int v=0;v<16;++v) arow[v] = sc[v]*inv;
  }
  __syncthreads();
  // phase C: wave = head
  const int wave = tid >> 6, lane = tid & 63;
  const int m = lane & 15, quad = lane >> 4;
  const int hh = hqq*4 + wave;
  const float* at = &attnT[wave*320];
  f32x4 acc[4];
  #pragma unroll
  for (int dt=0;dt<4;++dt) acc[dt] = (f32x4){0.f,0.f,0.f,0.f};
  #pragma unroll
  for (int vp=0; vp<8; ++vp){
    const int v = vp*2 + (quad>>1);
    const int k8 = (quad&1)*8;
    const float aw = at[m*20 + v];
    const float* pp = &patchP[m*260 + v*16 + k8];
    BF8 af;
    #pragma unroll
    for (int j=0;j<8;++j) af.s[j] = f2bu(aw*pp[j]);
    #pragma unroll
    for (int dt=0; dt<4; ++dt){
      const int d = hh*64 + dt*16 + m;
      const bf16x8 bf = *(const bf16x8*)(Wb2 + (size_t)d*256 + vp*32 + quad*8);
      acc[dt] = __builtin_amdgcn_mfma_f32_16x16x32_bf16(af.v, bf, acc[dt], 0,0,0);
    }
  }
  #pragma unroll
  for (int dt=0; dt<4; ++dt){
    const int d = hh*64 + dt*16 + m;
    const float* c0p = Cbig + (size_t)d*CN + 256;
    float c0v[16];
    #pragma unroll
    for (int j=0;j<4;++j){
      float4 t = *(const float4*)(c0p + 4*j);
      c0v[4*j+0]=t.x; c0v[4*j+1]=t.y; c0v[4*j+2]=t.z; c0v[4*j+3]=t.w;
    }
    const float bvd = bv[d];
    #pragma unroll
    for (int r=0;r<4;++r){
      const int s = quad*4 + r;
      float dot = bvd;   // sum_v attn = 1
      const float* as_ = at + s*20;
      #pragma unroll
      for (int v=0;v<16;++v) dot += as_[v]*c0v[v];
      ctx[(size_t)(l0+s)*D_ + d] = f2bu(acc[dt][r] + dot + P2[(size_t)(l0+s)*D_ + d]);
    }
  }
}

// ---------------------------------------------------------------------------
extern "C" void kernel_launch(void* const* d_in, const int* in_sizes, int n_in,
                              void* d_out, int out_size, void* d_ws, size_t ws_size,
                              hipStream_t stream){
  const float* x      = (const float*)d_in[0];
  const float* proj_w = (const float*)d_in[1];
  const float* proj_b = (const float*)d_in[2];
  const float* ce     = (const float*)d_in[3];
  const float* pe     = (const float*)d_in[4];
  const float* cq     = (const float*)d_in[5];
  const float* wq     = (const float*)d_in[6];
  const float* wk     = (const float*)d_in[7];
  const float* wv     = (const float*)d_in[8];
  const float* bq     = (const float*)d_in[9];
  // bk (d_in[10]) cancels in softmax
  const float* bv     = (const float*)d_in[11];
  const float* wo     = (const float*)d_in[12];
  const float* bo     = (const float*)d_in[13];
  float* out = (float*)d_out;

  // workspace — flat, ~24.1 MB used (ws ≈ 268 MB measured via poison-fill WRITE_SIZE)
  char* base = (char*)d_ws;
  unsigned short* Ab   = (unsigned short*)(base);              // [1152][1024] bf16 -> 2,359,296
  unsigned short* Btb  = (unsigned short*)(base + 2359296);    // [384][1024] bf16 -> 3,145,728
  float*          Cbig = (float*)(base + 3145728);             // [1040][384] f32 -> 4,743,168
  unsigned short* wo_b = (unsigned short*)(base + 4743168);    // [1024][1024] bf16 -> 6,840,320
  unsigned short* Wb2  = (unsigned short*)(base + 6840320);    // [1024][256] bf16 -> 7,364,608
  float*          P2   = (float*)(base + 7364608);             // [2048][1024] f32 -> 15,753,216
  unsigned short* ctxF = (unsigned short*)(base + 15753216);   // [4096][1024] bf16 -> 24,141,824

  // 1) prep: mcvt | tpB | q+qwk
  k_prep2<<<2560, 256, 0, stream>>>(wv, wo, proj_w, proj_b, ce, cq, wq, bq, wk, Ab, wo_b, Btb);
  // 2) Cbig (+Wb2)  ||  P2 = pe·wv^T (pe fp32-staged)
  k_gemmCP2<<<307, 256, 0, stream>>>(Ab, Btb, pe, Cbig, Wb2, P2);
  // 3) fused attention -> ctxF (both batches; 4-head blocks, 4 blocks/CU)
  k_fused7<<<1024, 256, 0, stream>>>(x, Cbig, Wb2, bv, P2, ctxF);
  // 4) out = ctxF·wo^T + bo
  k_gemmOut<<<dim3(8,64), 256, 0, stream>>>(ctxF, wo_b, bo, out);
}